// Round 1
// baseline (517.528 us; speedup 1.0000x reference)
//
#include <hip/hip_runtime.h>
#include <math.h>

#define N_ 2
#define L_ 2048
#define H_ 8
#define E_ 64
#define D_ 64
#define C_ 128                 // tile/chunk size
#define NC (L_/C_)             // 16
#define ROWSTRIDE (H_*E_)      // 512 floats between consecutive l
#define TEMP 0.125f            // 1/sqrt(64)
#define EPS_F 1e-6f
#define NEG_INF_F (-1e9f)
#define CHUNK_WS (E_*D_ + E_)  // 4160 floats per (n,h,chunk) ws entry

// Load a [128][64] f32 tile (rows stride 512 in global) into LDS, applying f(v4, row).
template <typename F>
__device__ __forceinline__ void load_tile(float* __restrict__ dst,
                                          const float* __restrict__ src_base,
                                          F f) {
  const int t = threadIdx.x;
#pragma unroll
  for (int k = 0; k < 8; ++k) {
    int idx4 = k * 256 + t;          // float4 index 0..2047
    int s = idx4 >> 4;               // row 0..127
    int e = (idx4 & 15) << 2;        // col 0..60
    float4 v = *(const float4*)(src_base + s * ROWSTRIDE + e);
    v = f(v, s);
    *(float4*)(dst + s * E_ + e) = v;
  }
}

// ---------------- Kernel 1: per-chunk local sums  sum K1 (E) and sum K1⊗V (E x D) ----
extern "C" __global__ void __launch_bounds__(256)
k_chunksums(const float* __restrict__ K, const float* __restrict__ V,
            const float* __restrict__ mask, float* __restrict__ ws) {
  __shared__ float kbuf[C_ * E_];
  __shared__ float vbuf[C_ * E_];
  const int bid = blockIdx.x;
  const int c = bid & (NC - 1), nh = bid >> 4, h = nh & (H_ - 1), n = nh >> 3;
  const int t = threadIdx.x;
  const int gbase = ((n * L_ + c * C_) * H_ + h) * E_;
  const float* mrow = mask + n * L_ + c * C_;

  load_tile(kbuf, K + gbase, [&](float4 v, int s) {
    float km = mrow[s];
    v.x = (tanhf(v.x) + 1.f) * km; v.y = (tanhf(v.y) + 1.f) * km;
    v.z = (tanhf(v.z) + 1.f) * km; v.w = (tanhf(v.w) + 1.f) * km;
    return v;
  });
  load_tile(vbuf, V + gbase, [&](float4 v, int) { return v; });
  __syncthreads();

  const int e0 = (t >> 4) << 2, d0 = (t & 15) << 2;
  float acc[4][4] = {};
  for (int s = 0; s < C_; ++s) {
    float4 kk = *(const float4*)(kbuf + s * E_ + e0);
    float4 vv = *(const float4*)(vbuf + s * E_ + d0);
    float ka[4] = {kk.x, kk.y, kk.z, kk.w};
    float va[4] = {vv.x, vv.y, vv.z, vv.w};
#pragma unroll
    for (int a = 0; a < 4; ++a)
#pragma unroll
      for (int b = 0; b < 4; ++b) acc[a][b] += ka[a] * va[b];
  }
  float* wsc = ws + (size_t)(nh * NC + c) * CHUNK_WS;
#pragma unroll
  for (int a = 0; a < 4; ++a) {
    float4 st = {acc[a][0], acc[a][1], acc[a][2], acc[a][3]};
    *(float4*)(wsc + (e0 + a) * D_ + d0) = st;
  }
  if (t < E_) {
    float sum = 0.f;
    for (int s = 0; s < C_; ++s) sum += kbuf[s * E_ + t];
    wsc[E_ * D_ + t] = sum;
  }
}

// ---------------- Kernel 2: exclusive prefix scan over the 16 chunks per (n,h) -------
extern "C" __global__ void __launch_bounds__(256)
k_scan(float* __restrict__ ws) {
  const int nh = blockIdx.x;
  const int t = threadIdx.x;
  float* base = ws + (size_t)nh * NC * CHUNK_WS;
  for (int k = 0; k < 16; ++k) {
    int idx = k * 256 + t;  // 0..4095 (KV)
    float acc = 0.f;
    for (int c = 0; c < NC; ++c) {
      float v = base[(size_t)c * CHUNK_WS + idx];
      base[(size_t)c * CHUNK_WS + idx] = acc;
      acc += v;
    }
  }
  if (t < E_) {
    int idx = E_ * D_ + t;  // Ksum
    float acc = 0.f;
    for (int c = 0; c < NC; ++c) {
      float v = base[(size_t)c * CHUNK_WS + idx];
      base[(size_t)c * CHUNK_WS + idx] = acc;
      acc += v;
    }
  }
}

// ---------------- Kernel 3: linear-attention path, writes (1-b)*LV to d_out ----------
extern "C" __global__ void __launch_bounds__(256, 1)
k_linear(const float* __restrict__ Q, const float* __restrict__ K,
         const float* __restrict__ V, const float* __restrict__ mask,
         const float* __restrict__ blend, const float* __restrict__ ws,
         float* __restrict__ out) {
  __shared__ float qbuf[C_ * E_];
  __shared__ float kbuf[C_ * E_];   // K1 in phase 1, V in phase 2
  __shared__ float sbuf[C_ * C_];
  __shared__ float zpart[C_];
  const int bid = blockIdx.x;
  const int c = bid & (NC - 1), nh = bid >> 4, h = nh & (H_ - 1), n = nh >> 3;
  const int t = threadIdx.x;
  const int gbase = ((n * L_ + c * C_) * H_ + h) * E_;
  const float* mrow = mask + n * L_ + c * C_;

  load_tile(qbuf, Q + gbase, [&](float4 v, int) {
    v.x = tanhf(v.x) + 1.f; v.y = tanhf(v.y) + 1.f;
    v.z = tanhf(v.z) + 1.f; v.w = tanhf(v.w) + 1.f;
    return v;
  });
  load_tile(kbuf, K + gbase, [&](float4 v, int s) {
    float km = mrow[s];
    v.x = (tanhf(v.x) + 1.f) * km; v.y = (tanhf(v.y) + 1.f) * km;
    v.z = (tanhf(v.z) + 1.f) * km; v.w = (tanhf(v.w) + 1.f) * km;
    return v;
  });
  __syncthreads();

  const float* wsc = ws + (size_t)(nh * NC + c) * CHUNK_WS;
  const int tl = t >> 4, td = t & 15;
  const int l0 = tl * 8, d0 = td * 4, sa0 = td * 8;

  // part 1: acc = Q1 @ S_start   (S_start read from global ws, L2-resident)
  float acc[8][4] = {};
  for (int e = 0; e < E_; ++e) {
    float4 sv4 = *(const float4*)(wsc + e * D_ + d0);
#pragma unroll
    for (int i = 0; i < 8; ++i) {
      float q = qbuf[(l0 + i) * E_ + e];
      acc[i][0] += q * sv4.x; acc[i][1] += q * sv4.y;
      acc[i][2] += q * sv4.z; acc[i][3] += q * sv4.w;
    }
  }
  // zpart[l] = Q1[l] . Ksum_start
  if (t < C_) {
    const float* ks = wsc + E_ * D_;
    float zz = 0.f;
    for (int e = 0; e < E_; ++e) zz += qbuf[t * E_ + e] * ks[e];
    zpart[t] = zz;
  }
  // A = tril(Q1 K1^T), 8x8 tile per thread, into sbuf
  float a[8][8] = {};
  for (int e = 0; e < E_; e += 4) {
    float4 kq[8];
#pragma unroll
    for (int jj = 0; jj < 8; ++jj)
      kq[jj] = *(const float4*)(kbuf + (sa0 + jj) * E_ + e);
#pragma unroll
    for (int i = 0; i < 8; ++i) {
      float4 q = *(const float4*)(qbuf + (l0 + i) * E_ + e);
#pragma unroll
      for (int jj = 0; jj < 8; ++jj)
        a[i][jj] += q.x * kq[jj].x + q.y * kq[jj].y + q.z * kq[jj].z + q.w * kq[jj].w;
    }
  }
#pragma unroll
  for (int i = 0; i < 8; ++i)
#pragma unroll
    for (int jj = 0; jj < 8; ++jj)
      sbuf[(l0 + i) * C_ + sa0 + jj] = (sa0 + jj <= l0 + i) ? a[i][jj] : 0.f;
  __syncthreads();

  load_tile(kbuf, V + gbase, [&](float4 v, int) { return v; });  // V over K1
  __syncthreads();

  float rsum[8] = {};
  for (int s = 0; s < C_; ++s) {
    float4 v4 = *(const float4*)(kbuf + s * E_ + d0);
#pragma unroll
    for (int i = 0; i < 8; ++i) {
      float p = sbuf[(l0 + i) * C_ + s];
      rsum[i] += p;
      acc[i][0] += p * v4.x; acc[i][1] += p * v4.y;
      acc[i][2] += p * v4.z; acc[i][3] += p * v4.w;
    }
  }
  const float bl = blend[0];
  const float ob = 1.f - bl;
#pragma unroll
  for (int i = 0; i < 8; ++i) {
    float z = 1.f / (zpart[l0 + i] + rsum[i] + EPS_F);
    float4 st;
    st.x = ob * acc[i][0] * z; st.y = ob * acc[i][1] * z;
    st.z = ob * acc[i][2] * z; st.w = ob * acc[i][3] * z;
    *(float4*)(out + gbase + (l0 + i) * ROWSTRIDE + d0) = st;
  }
}

// ---------------- Kernel 4: banded softmax path (flash stream), blends into d_out ----
extern "C" __global__ void __launch_bounds__(256, 1)
k_softmax(const float* __restrict__ Q, const float* __restrict__ K,
          const float* __restrict__ V, const float* __restrict__ mask,
          const float* __restrict__ blend, float* __restrict__ out) {
  __shared__ float qbuf[C_ * E_];
  __shared__ float kbuf[C_ * E_];   // K during S phase, V during PV phase
  __shared__ float sbuf[C_ * C_];   // scores, then banded P
  __shared__ float kmsk[C_];
  const int bid = blockIdx.x;
  const int qb = bid & (NC - 1), nh = bid >> 4, h = nh & (H_ - 1), n = nh >> 3;
  const int t = threadIdx.x;
  const int qgbase = ((n * L_ + qb * C_) * H_ + h) * E_;

  load_tile(qbuf, Q + qgbase, [&](float4 v, int) { return v; });
  __syncthreads();

  const int tl = t >> 4, td = t & 15;
  const int l0 = tl * 8, s0 = td * 8, d0 = td * 4;
  float m[8], dsum[8] = {};
  float acc[8][4] = {};
#pragma unroll
  for (int i = 0; i < 8; ++i) m[i] = -1e30f;

  for (int kb = 0; kb <= qb; ++kb) {
    const int kgbase = ((n * L_ + kb * C_) * H_ + h) * E_;
    load_tile(kbuf, K + kgbase, [&](float4 v, int) { return v; });
    if (t < C_) kmsk[t] = mask[n * L_ + kb * C_ + t];
    __syncthreads();

    // S tile (raw QK), 8x8 per thread
    float sv[8][8] = {};
    for (int e = 0; e < E_; e += 4) {
      float4 kq[8];
#pragma unroll
      for (int jj = 0; jj < 8; ++jj)
        kq[jj] = *(const float4*)(kbuf + (s0 + jj) * E_ + e);
#pragma unroll
      for (int i = 0; i < 8; ++i) {
        float4 q = *(const float4*)(qbuf + (l0 + i) * E_ + e);
#pragma unroll
        for (int jj = 0; jj < 8; ++jj)
          sv[i][jj] += q.x * kq[jj].x + q.y * kq[jj].y + q.z * kq[jj].z + q.w * kq[jj].w;
      }
    }
    const bool diag = (kb == qb);
    const bool prevb = (kb == qb - 1);
    const bool pv = (kb >= qb - 1);

#pragma unroll
    for (int i = 0; i < 8; ++i) {
      const int ll = l0 + i;
      float pm = -1e30f;
#pragma unroll
      for (int jj = 0; jj < 8; ++jj) {
        const int sl = s0 + jj;
        float x = sv[i][jj];
        x += (kmsk[sl] > 0.f) ? 0.f : NEG_INF_F;   // key_lengths mask
        if (diag && sl > ll) x += NEG_INF_F;       // causal
        x *= TEMP;
        sv[i][jj] = x;
        pm = fmaxf(pm, x);
      }
#pragma unroll
      for (int off = 1; off < 16; off <<= 1)
        pm = fmaxf(pm, __shfl_xor(pm, off));
      const float mn = fmaxf(m[i], pm);
      const float alpha = __expf(m[i] - mn);
      float ps = 0.f;
      float ev[8];
#pragma unroll
      for (int jj = 0; jj < 8; ++jj) {
        ev[jj] = __expf(sv[i][jj] - mn);
        ps += ev[jj];
      }
#pragma unroll
      for (int off = 1; off < 16; off <<= 1) ps += __shfl_xor(ps, off);
      dsum[i] = dsum[i] * alpha + ps;   // denominator over FULL causal range
      m[i] = mn;
      acc[i][0] *= alpha; acc[i][1] *= alpha; acc[i][2] *= alpha; acc[i][3] *= alpha;
      if (pv) {
        // banded numerator: for kb==qb-1 band is s_local >= l_local; kb==qb fully in band
#pragma unroll
        for (int jj = 0; jj < 8; ++jj) {
          const int sl = s0 + jj;
          float p = ev[jj];
          if (prevb && sl < ll) p = 0.f;
          sbuf[ll * C_ + sl] = p;
        }
      }
    }

    if (pv) {
      __syncthreads();
      load_tile(kbuf, V + kgbase, [&](float4 v, int) { return v; });
      __syncthreads();
      for (int s = 0; s < C_; ++s) {
        float4 v4 = *(const float4*)(kbuf + s * E_ + d0);
#pragma unroll
        for (int i = 0; i < 8; ++i) {
          float p = sbuf[(l0 + i) * C_ + s];
          acc[i][0] += p * v4.x; acc[i][1] += p * v4.y;
          acc[i][2] += p * v4.z; acc[i][3] += p * v4.w;
        }
      }
    }
    __syncthreads();
  }

  const float bl = blend[0];
#pragma unroll
  for (int i = 0; i < 8; ++i) {
    const float inv = 1.f / dsum[i];
    float* op = out + qgbase + (l0 + i) * ROWSTRIDE + d0;
    float4 pr = *(float4*)op;   // (1-b)*LV written by k_linear
    float4 st;
    st.x = bl * acc[i][0] * inv + pr.x;
    st.y = bl * acc[i][1] * inv + pr.y;
    st.z = bl * acc[i][2] * inv + pr.z;
    st.w = bl * acc[i][3] * inv + pr.w;
    *(float4*)op = st;
  }
}

extern "C" void kernel_launch(void* const* d_in, const int* in_sizes, int n_in,
                              void* d_out, int out_size, void* d_ws, size_t ws_size,
                              hipStream_t stream) {
  (void)in_sizes; (void)n_in; (void)out_size; (void)ws_size;
  const float* Q = (const float*)d_in[0];
  const float* K = (const float*)d_in[1];
  const float* V = (const float*)d_in[2];
  const float* mask = (const float*)d_in[3];
  const float* blend = (const float*)d_in[4];
  float* out = (float*)d_out;
  float* ws = (float*)d_ws;   // needs 256*4160*4 = ~4.06 MiB

  k_chunksums<<<dim3(N_ * H_ * NC), dim3(256), 0, stream>>>(K, V, mask, ws);
  k_scan<<<dim3(N_ * H_), dim3(256), 0, stream>>>(ws);
  k_linear<<<dim3(N_ * H_ * NC), dim3(256), 0, stream>>>(Q, K, V, mask, blend, ws, out);
  k_softmax<<<dim3(N_ * H_ * NC), dim3(256), 0, stream>>>(Q, K, V, mask, blend, out);
}

// Round 2
// 212.370 us; speedup vs baseline: 2.4369x; 2.4369x over previous
//
#include <hip/hip_runtime.h>
#include <math.h>

#define N_ 2
#define L_ 2048
#define H_ 8
#define E_ 64
#define D_ 64
#define C_ 128                 // tile/chunk size
#define NC (L_/C_)             // 16
#define ROWSTRIDE (H_*E_)      // 512 floats between consecutive l
#define TEMP 0.125f            // 1/sqrt(64)
#define EPS_F 1e-6f
#define NEG_INF_F (-1e9f)
#define CHUNK_WS (E_*D_ + E_)  // 4160 floats per (n,h,chunk) ws entry
#define PAD 68                 // padded LDS row stride (floats); 68*4B=272B=17*16B aligned, 68%32=4 banks
#define SPAD 132               // padded score-row stride

// Load a [128][64] f32 tile (rows stride 512 in global) into LDS with row stride RS.
template <int RS, typename F>
__device__ __forceinline__ void load_tile(float* __restrict__ dst,
                                          const float* __restrict__ src_base,
                                          F f) {
  const int t = threadIdx.x;
#pragma unroll
  for (int k = 0; k < 8; ++k) {
    int idx4 = k * 256 + t;          // float4 index 0..2047
    int s = idx4 >> 4;               // row 0..127
    int e = (idx4 & 15) << 2;        // col 0..60
    float4 v = *(const float4*)(src_base + s * ROWSTRIDE + e);
    v = f(v, s);
    *(float4*)(dst + s * RS + e) = v;
  }
}

// ---------------- Kernel 1: per-chunk local sums  sum K1 (E) and sum K1⊗V (E x D) ----
extern "C" __global__ void __launch_bounds__(256)
k_chunksums(const float* __restrict__ K, const float* __restrict__ V,
            const float* __restrict__ mask, float* __restrict__ ws) {
  __shared__ float kbuf[C_ * E_];
  __shared__ float vbuf[C_ * E_];
  const int bid = blockIdx.x;
  const int c = bid & (NC - 1), nh = bid >> 4, h = nh & (H_ - 1), n = nh >> 3;
  const int t = threadIdx.x;
  const int gbase = ((n * L_ + c * C_) * H_ + h) * E_;
  const float* mrow = mask + n * L_ + c * C_;

  load_tile<E_>(kbuf, K + gbase, [&](float4 v, int s) {
    float km = mrow[s];
    v.x = (tanhf(v.x) + 1.f) * km; v.y = (tanhf(v.y) + 1.f) * km;
    v.z = (tanhf(v.z) + 1.f) * km; v.w = (tanhf(v.w) + 1.f) * km;
    return v;
  });
  load_tile<E_>(vbuf, V + gbase, [&](float4 v, int) { return v; });
  __syncthreads();

  const int e0 = (t >> 4) << 2, d0 = (t & 15) << 2;
  float acc[4][4] = {};
  for (int s = 0; s < C_; ++s) {
    float4 kk = *(const float4*)(kbuf + s * E_ + e0);
    float4 vv = *(const float4*)(vbuf + s * E_ + d0);
    float ka[4] = {kk.x, kk.y, kk.z, kk.w};
    float va[4] = {vv.x, vv.y, vv.z, vv.w};
#pragma unroll
    for (int a = 0; a < 4; ++a)
#pragma unroll
      for (int b = 0; b < 4; ++b) acc[a][b] += ka[a] * va[b];
  }
  float* wsc = ws + (size_t)(nh * NC + c) * CHUNK_WS;
#pragma unroll
  for (int a = 0; a < 4; ++a) {
    float4 st = {acc[a][0], acc[a][1], acc[a][2], acc[a][3]};
    *(float4*)(wsc + (e0 + a) * D_ + d0) = st;
  }
  if (t < E_) {
    float sum = 0.f;
    for (int s = 0; s < C_; ++s) sum += kbuf[s * E_ + t];
    wsc[E_ * D_ + t] = sum;
  }
}

// ---------------- Kernel 2: exclusive prefix scan over the 16 chunks per (n,h) -------
extern "C" __global__ void __launch_bounds__(256)
k_scan(float* __restrict__ ws) {
  const int nh = blockIdx.x;
  const int t = threadIdx.x;
  float* base = ws + (size_t)nh * NC * CHUNK_WS;
  for (int k = 0; k < 16; ++k) {
    int idx = k * 256 + t;  // 0..4095 (KV)
    float acc = 0.f;
    for (int c = 0; c < NC; ++c) {
      float v = base[(size_t)c * CHUNK_WS + idx];
      base[(size_t)c * CHUNK_WS + idx] = acc;
      acc += v;
    }
  }
  if (t < E_) {
    int idx = E_ * D_ + t;  // Ksum
    float acc = 0.f;
    for (int c = 0; c < NC; ++c) {
      float v = base[(size_t)c * CHUNK_WS + idx];
      base[(size_t)c * CHUNK_WS + idx] = acc;
      acc += v;
    }
  }
}

// ---------------- Kernel 3: linear-attention path, writes (1-b)*LV to d_out ----------
extern "C" __global__ void __launch_bounds__(256, 1)
k_linear(const float* __restrict__ Q, const float* __restrict__ K,
         const float* __restrict__ V, const float* __restrict__ mask,
         const float* __restrict__ blend, const float* __restrict__ ws,
         float* __restrict__ out) {
  __shared__ float qbuf[C_ * E_];
  __shared__ float kbuf[C_ * E_];   // K1 in phase 1, V in phase 2
  __shared__ float sbuf[C_ * C_];
  __shared__ float zpart[C_];
  const int bid = blockIdx.x;
  const int c = bid & (NC - 1), nh = bid >> 4, h = nh & (H_ - 1), n = nh >> 3;
  const int t = threadIdx.x;
  const int gbase = ((n * L_ + c * C_) * H_ + h) * E_;
  const float* mrow = mask + n * L_ + c * C_;

  load_tile<E_>(qbuf, Q + gbase, [&](float4 v, int) {
    v.x = tanhf(v.x) + 1.f; v.y = tanhf(v.y) + 1.f;
    v.z = tanhf(v.z) + 1.f; v.w = tanhf(v.w) + 1.f;
    return v;
  });
  load_tile<E_>(kbuf, K + gbase, [&](float4 v, int s) {
    float km = mrow[s];
    v.x = (tanhf(v.x) + 1.f) * km; v.y = (tanhf(v.y) + 1.f) * km;
    v.z = (tanhf(v.z) + 1.f) * km; v.w = (tanhf(v.w) + 1.f) * km;
    return v;
  });
  __syncthreads();

  const float* wsc = ws + (size_t)(nh * NC + c) * CHUNK_WS;
  const int tl = t >> 4, td = t & 15;
  const int l0 = tl * 8, d0 = td * 4, sa0 = td * 8;

  // part 1: acc = Q1 @ S_start   (S_start read from global ws, L2-resident)
  float acc[8][4] = {};
  for (int e = 0; e < E_; ++e) {
    float4 sv4 = *(const float4*)(wsc + e * D_ + d0);
#pragma unroll
    for (int i = 0; i < 8; ++i) {
      float q = qbuf[(l0 + i) * E_ + e];
      acc[i][0] += q * sv4.x; acc[i][1] += q * sv4.y;
      acc[i][2] += q * sv4.z; acc[i][3] += q * sv4.w;
    }
  }
  // zpart[l] = Q1[l] . Ksum_start
  if (t < C_) {
    const float* ks = wsc + E_ * D_;
    float zz = 0.f;
    for (int e = 0; e < E_; ++e) zz += qbuf[t * E_ + e] * ks[e];
    zpart[t] = zz;
  }
  // A = tril(Q1 K1^T), 8x8 tile per thread, into sbuf
  float a[8][8] = {};
  for (int e = 0; e < E_; e += 4) {
    float4 kq[8];
#pragma unroll
    for (int jj = 0; jj < 8; ++jj)
      kq[jj] = *(const float4*)(kbuf + (sa0 + jj) * E_ + e);
#pragma unroll
    for (int i = 0; i < 8; ++i) {
      float4 q = *(const float4*)(qbuf + (l0 + i) * E_ + e);
#pragma unroll
      for (int jj = 0; jj < 8; ++jj)
        a[i][jj] += q.x * kq[jj].x + q.y * kq[jj].y + q.z * kq[jj].z + q.w * kq[jj].w;
    }
  }
#pragma unroll
  for (int i = 0; i < 8; ++i)
#pragma unroll
    for (int jj = 0; jj < 8; ++jj)
      sbuf[(l0 + i) * C_ + sa0 + jj] = (sa0 + jj <= l0 + i) ? a[i][jj] : 0.f;
  __syncthreads();

  load_tile<E_>(kbuf, V + gbase, [&](float4 v, int) { return v; });  // V over K1
  __syncthreads();

  float rsum[8] = {};
  for (int s = 0; s < C_; ++s) {
    float4 v4 = *(const float4*)(kbuf + s * E_ + d0);
#pragma unroll
    for (int i = 0; i < 8; ++i) {
      float p = sbuf[(l0 + i) * C_ + s];
      rsum[i] += p;
      acc[i][0] += p * v4.x; acc[i][1] += p * v4.y;
      acc[i][2] += p * v4.z; acc[i][3] += p * v4.w;
    }
  }
  const float bl = blend[0];
  const float ob = 1.f - bl;
#pragma unroll
  for (int i = 0; i < 8; ++i) {
    float z = 1.f / (zpart[l0 + i] + rsum[i] + EPS_F);
    float4 st;
    st.x = ob * acc[i][0] * z; st.y = ob * acc[i][1] * z;
    st.z = ob * acc[i][2] * z; st.w = ob * acc[i][3] * z;
    *(float4*)(out + gbase + (l0 + i) * ROWSTRIDE + d0) = st;
  }
}

// ---------------- Kernel 4: denominator partials, one block per (nh, qb, kb) ---------
// part[((nh*16+qb)*16+kb)*128 + l] = sum_s exp(temp*(QK + masks))   (no max-sub; safe in fp32)
extern "C" __global__ void __launch_bounds__(256, 2)
k_denom(const float* __restrict__ Q, const float* __restrict__ K,
        const float* __restrict__ mask, float* __restrict__ part) {
  __shared__ float qbuf[C_ * PAD];
  __shared__ float kbuf[C_ * PAD];
  __shared__ float kmsk[C_];
  const int bid = blockIdx.x;
  const int nh = bid / 136;
  const int p = bid - nh * 136;
  int qb = (int)((sqrtf(8.f * p + 1.f) - 1.f) * 0.5f);
  while ((qb + 1) * (qb + 2) / 2 <= p) ++qb;
  while (qb * (qb + 1) / 2 > p) --qb;
  const int kb = p - qb * (qb + 1) / 2;
  const int h = nh & (H_ - 1), n = nh >> 3;
  const int t = threadIdx.x;
  const int tl = t >> 4, td = t & 15;

  load_tile<PAD>(qbuf, Q + ((n * L_ + qb * C_) * H_ + h) * E_,
                 [&](float4 v, int) { return v; });
  load_tile<PAD>(kbuf, K + ((n * L_ + kb * C_) * H_ + h) * E_,
                 [&](float4 v, int) { return v; });
  if (t < C_) kmsk[t] = mask[n * L_ + kb * C_ + t];
  __syncthreads();

  // S tile: rows l = tl + 16i, cols s = td + 16j (interleaved: consecutive lanes
  // read consecutive K rows -> 2-way bank aliasing only)
  float sv[8][8] = {};
  for (int e = 0; e < E_; e += 4) {
    float4 kq[8];
#pragma unroll
    for (int jj = 0; jj < 8; ++jj)
      kq[jj] = *(const float4*)(kbuf + (td + 16 * jj) * PAD + e);
#pragma unroll
    for (int i = 0; i < 8; ++i) {
      float4 q = *(const float4*)(qbuf + (tl + 16 * i) * PAD + e);
#pragma unroll
      for (int jj = 0; jj < 8; ++jj)
        sv[i][jj] += q.x * kq[jj].x + q.y * kq[jj].y + q.z * kq[jj].z + q.w * kq[jj].w;
    }
  }

  const bool diag = (kb == qb);
  float* pout = part + (size_t)((nh * NC + qb) * NC + kb) * C_;
#pragma unroll
  for (int i = 0; i < 8; ++i) {
    const int ll = tl + 16 * i;
    float rs = 0.f;
#pragma unroll
    for (int jj = 0; jj < 8; ++jj) {
      const int sl = td + 16 * jj;
      float x = sv[i][jj];
      x += (kmsk[sl] > 0.f) ? 0.f : NEG_INF_F;
      if (diag && sl > ll) x += NEG_INF_F;
      rs += __expf(x * TEMP);
    }
#pragma unroll
    for (int off = 1; off < 16; off <<= 1) rs += __shfl_xor(rs, off);
    if (td == 0) pout[ll] = rs;
  }
}

// ---------------- Kernel 5: band PV + combine partials + blend into d_out ------------
extern "C" __global__ void __launch_bounds__(256, 1)
k_band(const float* __restrict__ Q, const float* __restrict__ K,
       const float* __restrict__ V, const float* __restrict__ mask,
       const float* __restrict__ blend, const float* __restrict__ part,
       float* __restrict__ out) {
  __shared__ float qbuf[C_ * PAD];
  __shared__ float kbuf[C_ * PAD];   // K during S phase, V during PV phase
  __shared__ float sbuf[C_ * SPAD];
  __shared__ float dinv[C_];
  __shared__ float kmsk[C_];
  const int bid = blockIdx.x;
  const int qb = bid & (NC - 1), nh = bid >> 4, h = nh & (H_ - 1), n = nh >> 3;
  const int t = threadIdx.x;
  const int tl = t >> 4, td = t & 15;
  const int qgbase = ((n * L_ + qb * C_) * H_ + h) * E_;

  load_tile<PAD>(qbuf, Q + qgbase, [&](float4 v, int) { return v; });
  if (t < C_) {
    const float* pp = part + (size_t)((nh * NC + qb) * NC) * C_ + t;
    float s = 0.f;
    for (int kb = 0; kb <= qb; ++kb) s += pp[kb * C_];
    dinv[t] = 1.f / s;
  }

  float acc[8][4] = {};
  const int kb0 = (qb > 0) ? qb - 1 : 0;
  for (int kb = kb0; kb <= qb; ++kb) {
    const int kgbase = ((n * L_ + kb * C_) * H_ + h) * E_;
    __syncthreads();
    load_tile<PAD>(kbuf, K + kgbase, [&](float4 v, int) { return v; });
    if (t < C_) kmsk[t] = mask[n * L_ + kb * C_ + t];
    __syncthreads();

    float sv[8][8] = {};
    for (int e = 0; e < E_; e += 4) {
      float4 kq[8];
#pragma unroll
      for (int jj = 0; jj < 8; ++jj)
        kq[jj] = *(const float4*)(kbuf + (td + 16 * jj) * PAD + e);
#pragma unroll
      for (int i = 0; i < 8; ++i) {
        float4 q = *(const float4*)(qbuf + (tl + 16 * i) * PAD + e);
#pragma unroll
        for (int jj = 0; jj < 8; ++jj)
          sv[i][jj] += q.x * kq[jj].x + q.y * kq[jj].y + q.z * kq[jj].z + q.w * kq[jj].w;
      }
    }
    const bool diag = (kb == qb);
    const bool prevb = (kb == qb - 1);
#pragma unroll
    for (int i = 0; i < 8; ++i) {
      const int ll = tl + 16 * i;
#pragma unroll
      for (int jj = 0; jj < 8; ++jj) {
        const int sl = td + 16 * jj;
        float x = sv[i][jj];
        x += (kmsk[sl] > 0.f) ? 0.f : NEG_INF_F;
        if (diag && sl > ll) x += NEG_INF_F;
        float e = __expf(x * TEMP);
        if (prevb && sl < ll) e = 0.f;     // band: keep s >= l - 128
        sbuf[ll * SPAD + sl] = e;
      }
    }
    __syncthreads();
    load_tile<PAD>(kbuf, V + kgbase, [&](float4 v, int) { return v; });
    __syncthreads();
    const int d0 = td * 4;
    for (int s = 0; s < C_; ++s) {
      float4 v4 = *(const float4*)(kbuf + s * PAD + d0);
#pragma unroll
      for (int i = 0; i < 8; ++i) {
        float p = sbuf[(tl + 16 * i) * SPAD + s];
        acc[i][0] += p * v4.x; acc[i][1] += p * v4.y;
        acc[i][2] += p * v4.z; acc[i][3] += p * v4.w;
      }
    }
  }

  const float bl = blend[0];
  const int d0 = td * 4;
#pragma unroll
  for (int i = 0; i < 8; ++i) {
    const int ll = tl + 16 * i;
    const float sc = bl * dinv[ll];
    float* op = out + qgbase + ll * ROWSTRIDE + d0;
    float4 pr = *(float4*)op;   // (1-b)*LV written by k_linear
    float4 st;
    st.x = sc * acc[i][0] + pr.x;
    st.y = sc * acc[i][1] + pr.y;
    st.z = sc * acc[i][2] + pr.z;
    st.w = sc * acc[i][3] + pr.w;
    *(float4*)op = st;
  }
}

extern "C" void kernel_launch(void* const* d_in, const int* in_sizes, int n_in,
                              void* d_out, int out_size, void* d_ws, size_t ws_size,
                              hipStream_t stream) {
  (void)in_sizes; (void)n_in; (void)out_size; (void)ws_size;
  const float* Q = (const float*)d_in[0];
  const float* K = (const float*)d_in[1];
  const float* V = (const float*)d_in[2];
  const float* mask = (const float*)d_in[3];
  const float* blend = (const float*)d_in[4];
  float* out = (float*)d_out;
  float* ws = (float*)d_ws;   // linear path: 256*4160 floats (~4.06 MiB)
  // denominator partials reuse the same region (k_denom runs after k_linear):
  float* part = ws;           // 256*16*128 floats = 2 MiB

  k_chunksums<<<dim3(N_ * H_ * NC), dim3(256), 0, stream>>>(K, V, mask, ws);
  k_scan<<<dim3(N_ * H_), dim3(256), 0, stream>>>(ws);
  k_linear<<<dim3(N_ * H_ * NC), dim3(256), 0, stream>>>(Q, K, V, mask, blend, ws, out);
  k_denom<<<dim3(N_ * H_ * 136), dim3(256), 0, stream>>>(Q, K, mask, part);
  k_band<<<dim3(N_ * H_ * NC), dim3(256), 0, stream>>>(Q, K, V, mask, blend, part, out);
}

// Round 3
// 150.269 us; speedup vs baseline: 3.4440x; 1.4133x over previous
//
#include <hip/hip_runtime.h>
#include <math.h>

#define N_ 2
#define L_ 2048
#define H_ 8
#define E_ 64
#define D_ 64
#define C_ 128                 // tile/chunk size
#define NC (L_/C_)             // 16
#define ROWSTRIDE (H_*E_)      // 512 floats between consecutive l
#define TEMP 0.125f            // 1/sqrt(64)
#define EPS_F 1e-6f
#define NEG_INF_F (-1e9f)
#define CHUNK_WS (E_*D_ + E_)  // 4160 floats per (n,h,chunk) ws entry
#define PAD 68                 // padded LDS row stride (floats)
#define SPAD 132               // padded score-row stride

typedef __attribute__((ext_vector_type(8))) short short8;   // 8 bf16 in 4 VGPRs
typedef __attribute__((ext_vector_type(4))) float f32x4;

__device__ __forceinline__ short f2bf(float x) {
  unsigned u = __float_as_uint(x);
  u += 0x7fffu + ((u >> 16) & 1u);   // round-to-nearest-even
  return (short)(u >> 16);
}

// Load a [128][64] f32 tile (rows stride 512 in global) into LDS with row stride RS.
template <int RS, typename F>
__device__ __forceinline__ void load_tile(float* __restrict__ dst,
                                          const float* __restrict__ src_base,
                                          F f) {
  const int t = threadIdx.x;
#pragma unroll
  for (int k = 0; k < 8; ++k) {
    int idx4 = k * 256 + t;          // float4 index 0..2047
    int s = idx4 >> 4;               // row 0..127
    int e = (idx4 & 15) << 2;        // col 0..60
    float4 v = *(const float4*)(src_base + s * ROWSTRIDE + e);
    v = f(v, s);
    *(float4*)(dst + s * RS + e) = v;
  }
}

// Load [128][64] f32 global tile -> bf16 LDS tile with XOR granule swizzle.
// LDS layout: row*64 shorts; 16B granule g at (g ^ (row&7)).
__device__ __forceinline__ void load_bf16_tile(short* __restrict__ dst,
                                               const float* __restrict__ src) {
  const int t = threadIdx.x;
#pragma unroll
  for (int it = 0; it < 4; ++it) {
    int gi = it * 256 + t;           // granule id 0..1023
    int row = gi >> 3, g = gi & 7;
    const float* p = src + row * ROWSTRIDE + g * 8;
    float4 a = *(const float4*)p;
    float4 b = *(const float4*)(p + 4);
    short8 v;
    v[0] = f2bf(a.x); v[1] = f2bf(a.y); v[2] = f2bf(a.z); v[3] = f2bf(a.w);
    v[4] = f2bf(b.x); v[5] = f2bf(b.y); v[6] = f2bf(b.z); v[7] = f2bf(b.w);
    int sg = g ^ (row & 7);
    *(short8*)(dst + row * 64 + sg * 8) = v;
  }
}

// Read an A/B fragment for mfma_f32_16x16x32_bf16 from a swizzled bf16 tile.
// rowbase: subtile base row; h: k-half (0 -> k 0..31, 1 -> k 32..63).
__device__ __forceinline__ short8 frag_ld(const short* __restrict__ buf,
                                          int rowbase, int h, int lane) {
  int r = rowbase + (lane & 15);
  int g = (h * 4 + (lane >> 4)) ^ (r & 7);
  return *(const short8*)(buf + r * 64 + g * 8);
}

// ---------------- Kernel 1: per-chunk local sums  sum K1 (E) and sum K1⊗V (E x D) ----
extern "C" __global__ void __launch_bounds__(256)
k_chunksums(const float* __restrict__ K, const float* __restrict__ V,
            const float* __restrict__ mask, float* __restrict__ ws) {
  __shared__ float kbuf[C_ * E_];
  __shared__ float vbuf[C_ * E_];
  const int bid = blockIdx.x;
  const int c = bid & (NC - 1), nh = bid >> 4, h = nh & (H_ - 1), n = nh >> 3;
  const int t = threadIdx.x;
  const int gbase = ((n * L_ + c * C_) * H_ + h) * E_;
  const float* mrow = mask + n * L_ + c * C_;

  load_tile<E_>(kbuf, K + gbase, [&](float4 v, int s) {
    float km = mrow[s];
    v.x = (tanhf(v.x) + 1.f) * km; v.y = (tanhf(v.y) + 1.f) * km;
    v.z = (tanhf(v.z) + 1.f) * km; v.w = (tanhf(v.w) + 1.f) * km;
    return v;
  });
  load_tile<E_>(vbuf, V + gbase, [&](float4 v, int) { return v; });
  __syncthreads();

  const int e0 = (t >> 4) << 2, d0 = (t & 15) << 2;
  float acc[4][4] = {};
  for (int s = 0; s < C_; ++s) {
    float4 kk = *(const float4*)(kbuf + s * E_ + e0);
    float4 vv = *(const float4*)(vbuf + s * E_ + d0);
    float ka[4] = {kk.x, kk.y, kk.z, kk.w};
    float va[4] = {vv.x, vv.y, vv.z, vv.w};
#pragma unroll
    for (int a = 0; a < 4; ++a)
#pragma unroll
      for (int b = 0; b < 4; ++b) acc[a][b] += ka[a] * va[b];
  }
  float* wsc = ws + (size_t)(nh * NC + c) * CHUNK_WS;
#pragma unroll
  for (int a = 0; a < 4; ++a) {
    float4 st = {acc[a][0], acc[a][1], acc[a][2], acc[a][3]};
    *(float4*)(wsc + (e0 + a) * D_ + d0) = st;
  }
  if (t < E_) {
    float sum = 0.f;
    for (int s = 0; s < C_; ++s) sum += kbuf[s * E_ + t];
    wsc[E_ * D_ + t] = sum;
  }
}

// ---------------- Kernel 2: exclusive prefix scan over the 16 chunks per (n,h) -------
extern "C" __global__ void __launch_bounds__(256)
k_scan(float* __restrict__ ws) {
  const int nh = blockIdx.x;
  const int t = threadIdx.x;
  float* base = ws + (size_t)nh * NC * CHUNK_WS;
  for (int k = 0; k < 16; ++k) {
    int idx = k * 256 + t;  // 0..4095 (KV)
    float acc = 0.f;
    for (int c = 0; c < NC; ++c) {
      float v = base[(size_t)c * CHUNK_WS + idx];
      base[(size_t)c * CHUNK_WS + idx] = acc;
      acc += v;
    }
  }
  if (t < E_) {
    int idx = E_ * D_ + t;  // Ksum
    float acc = 0.f;
    for (int c = 0; c < NC; ++c) {
      float v = base[(size_t)c * CHUNK_WS + idx];
      base[(size_t)c * CHUNK_WS + idx] = acc;
      acc += v;
    }
  }
}

// ---------------- Kernel 3: linear-attention path, writes (1-b)*LV to d_out ----------
extern "C" __global__ void __launch_bounds__(256, 1)
k_linear(const float* __restrict__ Q, const float* __restrict__ K,
         const float* __restrict__ V, const float* __restrict__ mask,
         const float* __restrict__ blend, const float* __restrict__ ws,
         float* __restrict__ out) {
  __shared__ float qbuf[C_ * PAD];
  __shared__ float kbuf[C_ * PAD];   // K1 in phase 1, V in phase 2
  __shared__ float sbuf[C_ * SPAD];
  __shared__ float zpart[C_];
  const int bid = blockIdx.x;
  const int c = bid & (NC - 1), nh = bid >> 4, h = nh & (H_ - 1), n = nh >> 3;
  const int t = threadIdx.x;
  const int gbase = ((n * L_ + c * C_) * H_ + h) * E_;
  const float* mrow = mask + n * L_ + c * C_;

  load_tile<PAD>(qbuf, Q + gbase, [&](float4 v, int) {
    v.x = tanhf(v.x) + 1.f; v.y = tanhf(v.y) + 1.f;
    v.z = tanhf(v.z) + 1.f; v.w = tanhf(v.w) + 1.f;
    return v;
  });
  load_tile<PAD>(kbuf, K + gbase, [&](float4 v, int s) {
    float km = mrow[s];
    v.x = (tanhf(v.x) + 1.f) * km; v.y = (tanhf(v.y) + 1.f) * km;
    v.z = (tanhf(v.z) + 1.f) * km; v.w = (tanhf(v.w) + 1.f) * km;
    return v;
  });
  __syncthreads();

  const float* wsc = ws + (size_t)(nh * NC + c) * CHUNK_WS;
  const int tl = t >> 4, td = t & 15;
  const int d0 = td * 4;

  // part 1: acc = Q1 @ S_start   (rows l = tl + 16i)
  float acc[8][4] = {};
  for (int e = 0; e < E_; ++e) {
    float4 sv4 = *(const float4*)(wsc + e * D_ + d0);
#pragma unroll
    for (int i = 0; i < 8; ++i) {
      float q = qbuf[(tl + 16 * i) * PAD + e];
      acc[i][0] += q * sv4.x; acc[i][1] += q * sv4.y;
      acc[i][2] += q * sv4.z; acc[i][3] += q * sv4.w;
    }
  }
  // zpart[l] = Q1[l] . Ksum_start
  if (t < C_) {
    const float* ks = wsc + E_ * D_;
    float zz = 0.f;
    for (int e = 0; e < E_; ++e) zz += qbuf[t * PAD + e] * ks[e];
    zpart[t] = zz;
  }
  // A = tril(Q1 K1^T): rows l = tl+16i, cols s = td+16j (interleaved, conflict-free)
  float a[8][8] = {};
  for (int e = 0; e < E_; e += 4) {
    float4 kq[8];
#pragma unroll
    for (int jj = 0; jj < 8; ++jj)
      kq[jj] = *(const float4*)(kbuf + (td + 16 * jj) * PAD + e);
#pragma unroll
    for (int i = 0; i < 8; ++i) {
      float4 q = *(const float4*)(qbuf + (tl + 16 * i) * PAD + e);
#pragma unroll
      for (int jj = 0; jj < 8; ++jj)
        a[i][jj] += q.x * kq[jj].x + q.y * kq[jj].y + q.z * kq[jj].z + q.w * kq[jj].w;
    }
  }
#pragma unroll
  for (int i = 0; i < 8; ++i)
#pragma unroll
    for (int jj = 0; jj < 8; ++jj) {
      const int row = tl + 16 * i, col = td + 16 * jj;
      sbuf[row * SPAD + col] = (col <= row) ? a[i][jj] : 0.f;
    }
  __syncthreads();

  load_tile<PAD>(kbuf, V + gbase, [&](float4 v, int) { return v; });  // V over K1
  __syncthreads();

  float rsum[8] = {};
  for (int s = 0; s < C_; ++s) {
    float4 v4 = *(const float4*)(kbuf + s * PAD + d0);
#pragma unroll
    for (int i = 0; i < 8; ++i) {
      float p = sbuf[(tl + 16 * i) * SPAD + s];
      rsum[i] += p;
      acc[i][0] += p * v4.x; acc[i][1] += p * v4.y;
      acc[i][2] += p * v4.z; acc[i][3] += p * v4.w;
    }
  }
  const float bl = blend[0];
  const float ob = 1.f - bl;
#pragma unroll
  for (int i = 0; i < 8; ++i) {
    const int ll = tl + 16 * i;
    float z = 1.f / (zpart[ll] + rsum[i] + EPS_F);
    float4 st;
    st.x = ob * acc[i][0] * z; st.y = ob * acc[i][1] * z;
    st.z = ob * acc[i][2] * z; st.w = ob * acc[i][3] * z;
    *(float4*)(out + gbase + ll * ROWSTRIDE + d0) = st;
  }
}

// ---------------- Kernel 4: denominator partials via bf16 MFMA -----------------------
// part[((nh*16+qb)*16+kb)*128 + l] = sum_s exp(temp*(QK + masks))
extern "C" __global__ void __launch_bounds__(256)
k_denom(const float* __restrict__ Q, const float* __restrict__ K,
        const float* __restrict__ mask, float* __restrict__ part) {
  __shared__ short qlds[C_ * E_];
  __shared__ short klds[C_ * E_];
  __shared__ float kmsk[C_];
  const int bid = blockIdx.x;
  const int nh = bid / 136;
  const int p = bid - nh * 136;
  int qb = (int)((sqrtf(8.f * p + 1.f) - 1.f) * 0.5f);
  while ((qb + 1) * (qb + 2) / 2 <= p) ++qb;
  while (qb * (qb + 1) / 2 > p) --qb;
  const int kb = p - qb * (qb + 1) / 2;
  const int h = nh & (H_ - 1), n = nh >> 3;
  const int t = threadIdx.x;

  load_bf16_tile(qlds, Q + ((n * L_ + qb * C_) * H_ + h) * E_);
  load_bf16_tile(klds, K + ((n * L_ + kb * C_) * H_ + h) * E_);
  if (t < C_) kmsk[t] = mask[n * L_ + kb * C_ + t];
  __syncthreads();

  const int w = t >> 6, lane = t & 63;
  const int rowbase = w * 32;           // wave's 32 output rows

  short8 afr[2][2];
#pragma unroll
  for (int m = 0; m < 2; ++m)
#pragma unroll
    for (int hh = 0; hh < 2; ++hh)
      afr[m][hh] = frag_ld(qlds, rowbase + 16 * m, hh, lane);

  f32x4 acc[2][8];
#pragma unroll
  for (int m = 0; m < 2; ++m)
#pragma unroll
    for (int c = 0; c < 8; ++c) acc[m][c] = (f32x4){0.f, 0.f, 0.f, 0.f};

#pragma unroll
  for (int c = 0; c < 8; ++c) {
    short8 b0 = frag_ld(klds, 16 * c, 0, lane);
    short8 b1 = frag_ld(klds, 16 * c, 1, lane);
#pragma unroll
    for (int m = 0; m < 2; ++m) {
      acc[m][c] = __builtin_amdgcn_mfma_f32_16x16x32_bf16(afr[m][0], b0, acc[m][c], 0, 0, 0);
      acc[m][c] = __builtin_amdgcn_mfma_f32_16x16x32_bf16(afr[m][1], b1, acc[m][c], 0, 0, 0);
    }
  }

  const bool diag = (kb == qb);
  const int col_lo = lane & 15;
  float* pout = part + (size_t)((nh * NC + qb) * NC + kb) * C_;
#pragma unroll
  for (int m = 0; m < 2; ++m) {
    const int rbase = rowbase + 16 * m + (lane >> 4) * 4;
    float rs[4] = {0.f, 0.f, 0.f, 0.f};
#pragma unroll
    for (int c = 0; c < 8; ++c) {
      const int col = 16 * c + col_lo;
      const float madd = (kmsk[col] > 0.f) ? 0.f : NEG_INF_F;
#pragma unroll
      for (int reg = 0; reg < 4; ++reg) {
        float x = acc[m][c][reg] + madd;
        if (diag && col > rbase + reg) x += NEG_INF_F;
        rs[reg] += __expf(x * TEMP);
      }
    }
#pragma unroll
    for (int off = 1; off < 16; off <<= 1) {
#pragma unroll
      for (int reg = 0; reg < 4; ++reg) rs[reg] += __shfl_xor(rs[reg], off);
    }
    if (col_lo == 0) {
#pragma unroll
      for (int reg = 0; reg < 4; ++reg) pout[rbase + reg] = rs[reg];
    }
  }
}

// ---------------- Kernel 5: band PV + combine partials + blend into d_out ------------
extern "C" __global__ void __launch_bounds__(256, 1)
k_band(const float* __restrict__ Q, const float* __restrict__ K,
       const float* __restrict__ V, const float* __restrict__ mask,
       const float* __restrict__ blend, const float* __restrict__ part,
       float* __restrict__ out) {
  __shared__ float qbuf[C_ * PAD];
  __shared__ float kbuf[C_ * PAD];   // K during S phase, V during PV phase
  __shared__ float sbuf[C_ * SPAD];
  __shared__ float dinv[C_];
  __shared__ float kmsk[C_];
  const int bid = blockIdx.x;
  const int qb = bid & (NC - 1), nh = bid >> 4, h = nh & (H_ - 1), n = nh >> 3;
  const int t = threadIdx.x;
  const int tl = t >> 4, td = t & 15;
  const int qgbase = ((n * L_ + qb * C_) * H_ + h) * E_;

  load_tile<PAD>(qbuf, Q + qgbase, [&](float4 v, int) { return v; });
  if (t < C_) {
    const float* pp = part + (size_t)((nh * NC + qb) * NC) * C_ + t;
    float s = 0.f;
    for (int kb = 0; kb <= qb; ++kb) s += pp[kb * C_];
    dinv[t] = 1.f / s;
  }

  float acc[8][4] = {};
  const int kb0 = (qb > 0) ? qb - 1 : 0;
  for (int kb = kb0; kb <= qb; ++kb) {
    const int kgbase = ((n * L_ + kb * C_) * H_ + h) * E_;
    __syncthreads();
    load_tile<PAD>(kbuf, K + kgbase, [&](float4 v, int) { return v; });
    if (t < C_) kmsk[t] = mask[n * L_ + kb * C_ + t];
    __syncthreads();

    float sv[8][8] = {};
    for (int e = 0; e < E_; e += 4) {
      float4 kq[8];
#pragma unroll
      for (int jj = 0; jj < 8; ++jj)
        kq[jj] = *(const float4*)(kbuf + (td + 16 * jj) * PAD + e);
#pragma unroll
      for (int i = 0; i < 8; ++i) {
        float4 q = *(const float4*)(qbuf + (tl + 16 * i) * PAD + e);
#pragma unroll
        for (int jj = 0; jj < 8; ++jj)
          sv[i][jj] += q.x * kq[jj].x + q.y * kq[jj].y + q.z * kq[jj].z + q.w * kq[jj].w;
      }
    }
    const bool diag = (kb == qb);
    const bool prevb = (kb == qb - 1);
#pragma unroll
    for (int i = 0; i < 8; ++i) {
      const int ll = tl + 16 * i;
#pragma unroll
      for (int jj = 0; jj < 8; ++jj) {
        const int sl = td + 16 * jj;
        float x = sv[i][jj];
        x += (kmsk[sl] > 0.f) ? 0.f : NEG_INF_F;
        if (diag && sl > ll) x += NEG_INF_F;
        float e = __expf(x * TEMP);
        if (prevb && sl < ll) e = 0.f;     // band: keep s >= l - 128
        sbuf[ll * SPAD + sl] = e;
      }
    }
    __syncthreads();
    load_tile<PAD>(kbuf, V + kgbase, [&](float4 v, int) { return v; });
    __syncthreads();
    const int d0 = td * 4;
    for (int s = 0; s < C_; ++s) {
      float4 v4 = *(const float4*)(kbuf + s * PAD + d0);
#pragma unroll
      for (int i = 0; i < 8; ++i) {
        float p = sbuf[(tl + 16 * i) * SPAD + s];
        acc[i][0] += p * v4.x; acc[i][1] += p * v4.y;
        acc[i][2] += p * v4.z; acc[i][3] += p * v4.w;
      }
    }
  }

  const float bl = blend[0];
  const int d0 = td * 4;
#pragma unroll
  for (int i = 0; i < 8; ++i) {
    const int ll = tl + 16 * i;
    const float sc = bl * dinv[ll];
    float* op = out + qgbase + ll * ROWSTRIDE + d0;
    float4 pr = *(float4*)op;   // (1-b)*LV written by k_linear
    float4 st;
    st.x = sc * acc[i][0] + pr.x;
    st.y = sc * acc[i][1] + pr.y;
    st.z = sc * acc[i][2] + pr.z;
    st.w = sc * acc[i][3] + pr.w;
    *(float4*)op = st;
  }
}

extern "C" void kernel_launch(void* const* d_in, const int* in_sizes, int n_in,
                              void* d_out, int out_size, void* d_ws, size_t ws_size,
                              hipStream_t stream) {
  (void)in_sizes; (void)n_in; (void)out_size; (void)ws_size;
  const float* Q = (const float*)d_in[0];
  const float* K = (const float*)d_in[1];
  const float* V = (const float*)d_in[2];
  const float* mask = (const float*)d_in[3];
  const float* blend = (const float*)d_in[4];
  float* out = (float*)d_out;
  float* ws = (float*)d_ws;   // linear path: 256*4160 floats (~4.06 MiB)
  // denominator partials reuse the same region (k_denom runs after k_linear):
  float* part = ws;           // 256*16*128 floats = 2 MiB

  k_chunksums<<<dim3(N_ * H_ * NC), dim3(256), 0, stream>>>(K, V, mask, ws);
  k_scan<<<dim3(N_ * H_), dim3(256), 0, stream>>>(ws);
  k_linear<<<dim3(N_ * H_ * NC), dim3(256), 0, stream>>>(Q, K, V, mask, blend, ws, out);
  k_denom<<<dim3(N_ * H_ * 136), dim3(256), 0, stream>>>(Q, K, mask, part);
  k_band<<<dim3(N_ * H_ * NC), dim3(256), 0, stream>>>(Q, K, V, mask, blend, part, out);
}

// Round 4
// 86.801 us; speedup vs baseline: 5.9622x; 1.7312x over previous
//
#include <hip/hip_runtime.h>
#include <math.h>

#define N_ 2
#define L_ 2048
#define H_ 8
#define E_ 64
#define D_ 64
#define C_ 128                 // chunk size
#define NC (L_/C_)             // 16
#define ROWSTRIDE (H_*E_)      // 512 floats between consecutive l
#define TEMP 0.125f            // 1/sqrt(64)
#define EPS_F 1e-6f
#define NEG_INF_F (-1e9f)
#define CHUNK_WS (E_*D_ + E_)  // 4160 floats per (n,h,chunk) ws entry
#define NCHUNKS (N_*H_*NC)     // 256
#define TPAD 136               // transposed bf16 tile row stride (shorts; 272B, 16B-aligned)
#define PPAD 72                // pbuf row stride (shorts; 144B, 16B-aligned)

typedef __attribute__((ext_vector_type(8))) short short8;   // 8 bf16 in 4 VGPRs
typedef __attribute__((ext_vector_type(4))) float f32x4;

__device__ __forceinline__ short f2bf(float x) {
  unsigned u = __float_as_uint(x);
  u += 0x7fffu + ((u >> 16) & 1u);   // round-to-nearest-even
  return (short)(u >> 16);
}
__device__ __forceinline__ float bf2f(short s) {
  return __uint_as_float(((unsigned)(unsigned short)s) << 16);
}

// Load a [128][64] f32 tile (rows stride 512 in global) into LDS with row stride RS.
template <int RS, typename F>
__device__ __forceinline__ void load_tile(float* __restrict__ dst,
                                          const float* __restrict__ src_base,
                                          F f) {
  const int t = threadIdx.x;
#pragma unroll
  for (int k = 0; k < 8; ++k) {
    int idx4 = k * 256 + t;
    int s = idx4 >> 4;
    int e = (idx4 & 15) << 2;
    float4 v = *(const float4*)(src_base + s * ROWSTRIDE + e);
    v = f(v, s);
    *(float4*)(dst + s * RS + e) = v;
  }
}

// Load [128][64] f32 global tile -> bf16 LDS tile with XOR granule swizzle.
__device__ __forceinline__ void load_bf16_tile(short* __restrict__ dst,
                                               const float* __restrict__ src) {
  const int t = threadIdx.x;
#pragma unroll
  for (int it = 0; it < 4; ++it) {
    int gi = it * 256 + t;
    int row = gi >> 3, g = gi & 7;
    const float* p = src + row * ROWSTRIDE + g * 8;
    float4 a = *(const float4*)p;
    float4 b = *(const float4*)(p + 4);
    short8 v;
    v[0] = f2bf(a.x); v[1] = f2bf(a.y); v[2] = f2bf(a.z); v[3] = f2bf(a.w);
    v[4] = f2bf(b.x); v[5] = f2bf(b.y); v[6] = f2bf(b.z); v[7] = f2bf(b.w);
    int sg = g ^ (row & 7);
    *(short8*)(dst + row * 64 + sg * 8) = v;
  }
}

// A/B fragment from swizzled row-major bf16 tile ([rows][64], granule XOR swizzle).
__device__ __forceinline__ short8 frag_ld(const short* __restrict__ buf,
                                          int rowbase, int hf, int lane) {
  int r = rowbase + (lane & 15);
  int g = (hf * 4 + (lane >> 4)) ^ (r & 7);
  return *(const short8*)(buf + r * 64 + g * 8);
}

// B fragment from transposed padded tile [64][TPAD]: row = n, cols = k contiguous.
__device__ __forceinline__ short8 frag_ldT(const short* __restrict__ buf,
                                           int nbase, int g, int lane) {
  int r = nbase + (lane & 15);
  return *(const short8*)(buf + r * TPAD + g * 8);
}

// A fragment from pbuf [64][PPAD] (plain padded layout).
__device__ __forceinline__ short8 frag_ldP(const short* __restrict__ buf,
                                           int rowbase, int ks, int lane) {
  int r = rowbase + (lane & 15);
  int g = ks * 4 + (lane >> 4);
  return *(const short8*)(buf + r * PPAD + g * 8);
}

// ---------------- Kernel 1: per-chunk local sums  sum K1 (E) and sum K1⊗V (E x D) ----
extern "C" __global__ void __launch_bounds__(256)
k_chunksums(const float* __restrict__ K, const float* __restrict__ V,
            const float* __restrict__ mask, float* __restrict__ ws) {
  __shared__ float kbuf[C_ * E_];
  __shared__ float vbuf[C_ * E_];
  const int bid = blockIdx.x;
  const int c = bid & (NC - 1), nh = bid >> 4, h = nh & (H_ - 1), n = nh >> 3;
  const int t = threadIdx.x;
  const int gbase = ((n * L_ + c * C_) * H_ + h) * E_;
  const float* mrow = mask + n * L_ + c * C_;

  load_tile<E_>(kbuf, K + gbase, [&](float4 v, int s) {
    float km = mrow[s];
    v.x = (tanhf(v.x) + 1.f) * km; v.y = (tanhf(v.y) + 1.f) * km;
    v.z = (tanhf(v.z) + 1.f) * km; v.w = (tanhf(v.w) + 1.f) * km;
    return v;
  });
  load_tile<E_>(vbuf, V + gbase, [&](float4 v, int) { return v; });
  __syncthreads();

  const int e0 = (t >> 4) << 2, d0 = (t & 15) << 2;
  float acc[4][4] = {};
  for (int s = 0; s < C_; ++s) {
    float4 kk = *(const float4*)(kbuf + s * E_ + e0);
    float4 vv = *(const float4*)(vbuf + s * E_ + d0);
    float ka[4] = {kk.x, kk.y, kk.z, kk.w};
    float va[4] = {vv.x, vv.y, vv.z, vv.w};
#pragma unroll
    for (int a = 0; a < 4; ++a)
#pragma unroll
      for (int b = 0; b < 4; ++b) acc[a][b] += ka[a] * va[b];
  }
  float* wsc = ws + (size_t)(nh * NC + c) * CHUNK_WS;
#pragma unroll
  for (int a = 0; a < 4; ++a) {
    float4 st = {acc[a][0], acc[a][1], acc[a][2], acc[a][3]};
    *(float4*)(wsc + (e0 + a) * D_ + d0) = st;
  }
  if (t < E_) {
    float sum = 0.f;
    for (int s = 0; s < C_; ++s) sum += kbuf[s * E_ + t];
    wsc[E_ * D_ + t] = sum;
  }
}

// ---------------- Kernel 2: exclusive prefix scan over the 16 chunks per (n,h) -------
extern "C" __global__ void __launch_bounds__(256)
k_scan(float* __restrict__ ws) {
  const int nh = blockIdx.x;
  const int t = threadIdx.x;
  float* base = ws + (size_t)nh * NC * CHUNK_WS;
  for (int k = 0; k < 16; ++k) {
    int idx = k * 256 + t;
    float acc = 0.f;
    for (int c = 0; c < NC; ++c) {
      float v = base[(size_t)c * CHUNK_WS + idx];
      base[(size_t)c * CHUNK_WS + idx] = acc;
      acc += v;
    }
  }
  if (t < E_) {
    int idx = E_ * D_ + t;
    float acc = 0.f;
    for (int c = 0; c < NC; ++c) {
      float v = base[(size_t)c * CHUNK_WS + idx];
      base[(size_t)c * CHUNK_WS + idx] = acc;
      acc += v;
    }
  }
}

// ---------------- Kernel 3: denominator partials via bf16 MFMA -----------------------
extern "C" __global__ void __launch_bounds__(256)
k_denom(const float* __restrict__ Q, const float* __restrict__ K,
        const float* __restrict__ mask, float* __restrict__ part) {
  __shared__ short qlds[C_ * E_];
  __shared__ short klds[C_ * E_];
  __shared__ float kmsk[C_];
  const int bid = blockIdx.x;
  const int nh = bid / 136;
  const int p = bid - nh * 136;
  int qb = (int)((sqrtf(8.f * p + 1.f) - 1.f) * 0.5f);
  while ((qb + 1) * (qb + 2) / 2 <= p) ++qb;
  while (qb * (qb + 1) / 2 > p) --qb;
  const int kb = p - qb * (qb + 1) / 2;
  const int h = nh & (H_ - 1), n = nh >> 3;
  const int t = threadIdx.x;

  load_bf16_tile(qlds, Q + ((n * L_ + qb * C_) * H_ + h) * E_);
  load_bf16_tile(klds, K + ((n * L_ + kb * C_) * H_ + h) * E_);
  if (t < C_) kmsk[t] = mask[n * L_ + kb * C_ + t];
  __syncthreads();

  const int w = t >> 6, lane = t & 63;
  const int rowbase = w * 32;

  short8 afr[2][2];
#pragma unroll
  for (int m = 0; m < 2; ++m)
#pragma unroll
    for (int hh = 0; hh < 2; ++hh)
      afr[m][hh] = frag_ld(qlds, rowbase + 16 * m, hh, lane);

  f32x4 acc[2][8];
#pragma unroll
  for (int m = 0; m < 2; ++m)
#pragma unroll
    for (int c = 0; c < 8; ++c) acc[m][c] = (f32x4){0.f, 0.f, 0.f, 0.f};

#pragma unroll
  for (int c = 0; c < 8; ++c) {
    short8 b0 = frag_ld(klds, 16 * c, 0, lane);
    short8 b1 = frag_ld(klds, 16 * c, 1, lane);
#pragma unroll
    for (int m = 0; m < 2; ++m) {
      acc[m][c] = __builtin_amdgcn_mfma_f32_16x16x32_bf16(afr[m][0], b0, acc[m][c], 0, 0, 0);
      acc[m][c] = __builtin_amdgcn_mfma_f32_16x16x32_bf16(afr[m][1], b1, acc[m][c], 0, 0, 0);
    }
  }

  const bool diag = (kb == qb);
  const int col_lo = lane & 15;
  float* pout = part + (size_t)((nh * NC + qb) * NC + kb) * C_;
#pragma unroll
  for (int m = 0; m < 2; ++m) {
    const int rbase = rowbase + 16 * m + (lane >> 4) * 4;
    float rs[4] = {0.f, 0.f, 0.f, 0.f};
#pragma unroll
    for (int c = 0; c < 8; ++c) {
      const int col = 16 * c + col_lo;
      const float madd = (kmsk[col] > 0.f) ? 0.f : NEG_INF_F;
#pragma unroll
      for (int reg = 0; reg < 4; ++reg) {
        float x = acc[m][c][reg] + madd;
        if (diag && col > rbase + reg) x += NEG_INF_F;
        rs[reg] += __expf(x * TEMP);
      }
    }
#pragma unroll
    for (int off = 1; off < 16; off <<= 1) {
#pragma unroll
      for (int reg = 0; reg < 4; ++reg) rs[reg] += __shfl_xor(rs[reg], off);
    }
    if (col_lo == 0) {
#pragma unroll
      for (int reg = 0; reg < 4; ++reg) pout[rbase + reg] = rs[reg];
    }
  }
}

// ---------------- Kernel 4: fused linear + banded-softmax, full MFMA -----------------
// One block per (n, h, chunk qb, row-half rh): 64 query rows, writes out once.
extern "C" __global__ void __launch_bounds__(256, 2)
k_fused(const float* __restrict__ Q, const float* __restrict__ K,
        const float* __restrict__ V, const float* __restrict__ mask,
        const float* __restrict__ blend, const float* __restrict__ ws,
        const float* __restrict__ part, float* __restrict__ out) {
  __shared__ short qs[64 * 64];      // raw Q bf16 (swizzled rows)
  __shared__ short q1[64 * 64];      // tanh(Q)+1 bf16
  __shared__ short kv[64 * TPAD];    // union: [128][64] swizzled (8192 sh) / [64][TPAD] transposed
  __shared__ short pbuf[64 * PPAD];  // P-hat half-tile, bf16, padded
  __shared__ float zlds[64];
  __shared__ float dinv[64];
  __shared__ float ksum[E_];
  __shared__ float kmsk[C_];

  const int bid = blockIdx.x;
  const int rh = bid & 1, qb = (bid >> 1) & (NC - 1), nh = bid >> 5;
  const int h = nh & (H_ - 1), n = nh >> 3;
  const int t = threadIdx.x;
  const int w = t >> 6, lane = t & 63;
  const int rowbase = w * 16;              // wave's 16 local rows
  const int col_lo = lane & 15;
  const int rb = rowbase + ((lane >> 4) << 2);   // +reg = local row (0..63)
  const int rtile0 = rh * 64 + rb;               // row in 128-chunk coords (+reg)
  const int qgbase = ((n * L_ + qb * C_ + rh * 64) * H_ + h) * E_;
  const int kbase_chunk = ((n * L_ + qb * C_) * H_ + h) * E_;
  const float* wsc = ws + (size_t)(nh * NC + qb) * CHUNK_WS;
  const float bl = blend[0];
  const float ob = 1.f - bl;

  // ---- stage: Q dual (64 rows), K1 chunk (128 rows), ksum, dinv ----
#pragma unroll
  for (int it = 0; it < 2; ++it) {
    int gi = it * 256 + t, row = gi >> 3, g = gi & 7;
    const float* p = Q + qgbase + row * ROWSTRIDE + g * 8;
    float4 a = *(const float4*)p, b = *(const float4*)(p + 4);
    float xs[8] = {a.x, a.y, a.z, a.w, b.x, b.y, b.z, b.w};
    short8 vs, v1;
#pragma unroll
    for (int j = 0; j < 8; ++j) {
      vs[j] = f2bf(xs[j]);
      v1[j] = f2bf(tanhf(xs[j]) + 1.f);
    }
    int sg = g ^ (row & 7);
    *(short8*)(qs + row * 64 + sg * 8) = vs;
    *(short8*)(q1 + row * 64 + sg * 8) = v1;
  }
  {
    const float* mrow = mask + n * L_ + qb * C_;
#pragma unroll
    for (int it = 0; it < 4; ++it) {
      int gi = it * 256 + t, row = gi >> 3, g = gi & 7;
      const float* p = K + kbase_chunk + row * ROWSTRIDE + g * 8;
      float4 a = *(const float4*)p, b = *(const float4*)(p + 4);
      float km = mrow[row];
      float xs[8] = {a.x, a.y, a.z, a.w, b.x, b.y, b.z, b.w};
      short8 v1;
#pragma unroll
      for (int j = 0; j < 8; ++j) v1[j] = f2bf((tanhf(xs[j]) + 1.f) * km);
      int sg = g ^ (row & 7);
      *(short8*)(kv + row * 64 + sg * 8) = v1;
    }
  }
  if (t < E_) ksum[t] = wsc[E_ * D_ + t];
  if (t < 64) {
    const float* pp = part + (size_t)((nh * NC + qb) * NC) * C_ + rh * 64 + t;
    float s = 0.f;
    for (int kb = 0; kb <= qb; ++kb) s += pp[kb * C_];
    dinv[t] = 1.f / s;
  }
  __syncthreads();   // B1

  short8 af1[2];
#pragma unroll
  for (int kh = 0; kh < 2; ++kh) af1[kh] = frag_ld(q1, rowbase, kh, lane);

  // Q1 K1^T over full 128-col chunk
  f32x4 c1[8];
#pragma unroll
  for (int ct = 0; ct < 8; ++ct) c1[ct] = (f32x4){0.f, 0.f, 0.f, 0.f};
#pragma unroll
  for (int ct = 0; ct < 8; ++ct) {
    short8 b0 = frag_ld(kv, 16 * ct, 0, lane);
    short8 b1 = frag_ld(kv, 16 * ct, 1, lane);
    c1[ct] = __builtin_amdgcn_mfma_f32_16x16x32_bf16(af1[0], b0, c1[ct], 0, 0, 0);
    c1[ct] = __builtin_amdgcn_mfma_f32_16x16x32_bf16(af1[1], b1, c1[ct], 0, 0, 0);
  }
  // zpart = Q1 . Ksum_start
  if (t < 64) {
    float zz = 0.f;
#pragma unroll
    for (int gg = 0; gg < 8; ++gg) {
      int g = (gg + (t >> 3)) & 7;
      short8 v = *(const short8*)(q1 + t * 64 + ((g ^ (t & 7)) * 8));
#pragma unroll
      for (int j = 0; j < 8; ++j) zz += bf2f(v[j]) * ksum[g * 8 + j];
    }
    zlds[t] = zz;
  }
  __syncthreads();   // B2: kv free, zlds ready

  // stage S^T (bf16) into kv
  {
    int d = t & 63, eb = t >> 6;
#pragma unroll
    for (int q = 0; q < 2; ++q) {
      int e0 = eb * 16 + q * 8;
      short8 v;
#pragma unroll
      for (int j = 0; j < 8; ++j) v[j] = f2bf(wsc[(e0 + j) * D_ + d]);
      *(short8*)(kv + d * TPAD + (e0 >> 3) * 8) = v;
    }
  }
  // tril mask + row sums + z
  float zr[4];
  {
    float rs[4] = {0.f, 0.f, 0.f, 0.f};
#pragma unroll
    for (int ct = 0; ct < 8; ++ct) {
      int col = 16 * ct + col_lo;
#pragma unroll
      for (int reg = 0; reg < 4; ++reg) {
        if (col <= rtile0 + reg) rs[reg] += c1[ct][reg];
        else c1[ct][reg] = 0.f;
      }
    }
#pragma unroll
    for (int off = 1; off < 16; off <<= 1)
#pragma unroll
      for (int reg = 0; reg < 4; ++reg) rs[reg] += __shfl_xor(rs[reg], off);
    f32x4 zp = *(const f32x4*)(zlds + rb);
#pragma unroll
    for (int reg = 0; reg < 4; ++reg) zr[reg] = ob / (zp[reg] + rs[reg] + EPS_F);
  }
  __syncthreads();   // B3: S^T ready

  // accL = Q1 @ S_start, then scale rows by z*(1-b)
  f32x4 accL[4];
#pragma unroll
  for (int nn = 0; nn < 4; ++nn) accL[nn] = (f32x4){0.f, 0.f, 0.f, 0.f};
#pragma unroll
  for (int ks = 0; ks < 2; ++ks) {
    short8 bf[4];
#pragma unroll
    for (int nn = 0; nn < 4; ++nn)
      bf[nn] = frag_ldT(kv, 16 * nn, ks * 4 + (lane >> 4), lane);
#pragma unroll
    for (int nn = 0; nn < 4; ++nn)
      accL[nn] = __builtin_amdgcn_mfma_f32_16x16x32_bf16(af1[ks], bf[nn], accL[nn], 0, 0, 0);
  }
#pragma unroll
  for (int nn = 0; nn < 4; ++nn)
#pragma unroll
    for (int reg = 0; reg < 4; ++reg) accL[nn][reg] *= zr[reg];
  __syncthreads();   // B4: kv free

  // stage V^T (chunk) into kv
  {
    int d = t & 63, sb = t >> 6;
#pragma unroll
    for (int q = 0; q < 4; ++q) {
      int s0 = sb * 32 + q * 8;
      short8 v;
#pragma unroll
      for (int j = 0; j < 8; ++j) v[j] = f2bf(V[kbase_chunk + (s0 + j) * ROWSTRIDE + d]);
      *(short8*)(kv + d * TPAD + (s0 >> 3) * 8) = v;
    }
  }
  __syncthreads();   // B5

  // accL += P1_hat @ V   (P1_hat = tril(Q1K1^T) * z * (1-b), bf16)
#pragma unroll
  for (int hh = 0; hh < 2; ++hh) {
#pragma unroll
    for (int ch = 0; ch < 4; ++ch) {
      int ct = 4 * hh + ch;
      int colh = 16 * ch + col_lo;
#pragma unroll
      for (int reg = 0; reg < 4; ++reg)
        pbuf[(rb + reg) * PPAD + colh] = f2bf(c1[ct][reg] * zr[reg]);
    }
#pragma unroll
    for (int ks = 0; ks < 2; ++ks) {
      short8 ap = frag_ldP(pbuf, rowbase, ks, lane);
      short8 bv[4];
#pragma unroll
      for (int nn = 0; nn < 4; ++nn)
        bv[nn] = frag_ldT(kv, 16 * nn, 8 * hh + ks * 4 + (lane >> 4), lane);
#pragma unroll
      for (int nn = 0; nn < 4; ++nn)
        accL[nn] = __builtin_amdgcn_mfma_f32_16x16x32_bf16(ap, bv[nn], accL[nn], 0, 0, 0);
    }
  }

  // ---- banded softmax phase ----
  short8 afs[2];
#pragma unroll
  for (int kh = 0; kh < 2; ++kh) afs[kh] = frag_ld(qs, rowbase, kh, lane);
  f32x4 accS[4];
#pragma unroll
  for (int nn = 0; nn < 4; ++nn) accS[nn] = (f32x4){0.f, 0.f, 0.f, 0.f};
  f32x4 dv = *(const f32x4*)(dinv + rb);

  const int kblo = (qb > 0) ? qb - 1 : qb;
  for (int kb = kblo; kb <= qb; ++kb) {
    __syncthreads();   // kv + pbuf free from previous use
    const int kg = ((n * L_ + kb * C_) * H_ + h) * E_;
#pragma unroll
    for (int it = 0; it < 4; ++it) {
      int gi = it * 256 + t, row = gi >> 3, g = gi & 7;
      const float* p = K + kg + row * ROWSTRIDE + g * 8;
      float4 a = *(const float4*)p, b = *(const float4*)(p + 4);
      short8 v;
      v[0] = f2bf(a.x); v[1] = f2bf(a.y); v[2] = f2bf(a.z); v[3] = f2bf(a.w);
      v[4] = f2bf(b.x); v[5] = f2bf(b.y); v[6] = f2bf(b.z); v[7] = f2bf(b.w);
      int sg = g ^ (row & 7);
      *(short8*)(kv + row * 64 + sg * 8) = v;
    }
    if (t < C_) kmsk[t] = mask[n * L_ + kb * C_ + t];
    __syncthreads();

    f32x4 cs[8];
#pragma unroll
    for (int ct = 0; ct < 8; ++ct) cs[ct] = (f32x4){0.f, 0.f, 0.f, 0.f};
#pragma unroll
    for (int ct = 0; ct < 8; ++ct) {
      short8 b0 = frag_ld(kv, 16 * ct, 0, lane);
      short8 b1 = frag_ld(kv, 16 * ct, 1, lane);
      cs[ct] = __builtin_amdgcn_mfma_f32_16x16x32_bf16(afs[0], b0, cs[ct], 0, 0, 0);
      cs[ct] = __builtin_amdgcn_mfma_f32_16x16x32_bf16(afs[1], b1, cs[ct], 0, 0, 0);
    }
    const bool diag = (kb == qb), prevb = (kb != qb);
#pragma unroll
    for (int ct = 0; ct < 8; ++ct) {
      int col = 16 * ct + col_lo;
      float madd = (kmsk[col] > 0.f) ? 0.f : NEG_INF_F;
#pragma unroll
      for (int reg = 0; reg < 4; ++reg) {
        float x = cs[ct][reg] + madd;
        if (diag && col > rtile0 + reg) x += NEG_INF_F;
        cs[ct][reg] = x;
      }
    }
    __syncthreads();   // kv reads done
    {
      int d = t & 63, sb = t >> 6;
#pragma unroll
      for (int q = 0; q < 4; ++q) {
        int s0 = sb * 32 + q * 8;
        short8 v;
#pragma unroll
        for (int j = 0; j < 8; ++j) v[j] = f2bf(V[kg + (s0 + j) * ROWSTRIDE + d]);
        *(short8*)(kv + d * TPAD + (s0 >> 3) * 8) = v;
      }
    }
    __syncthreads();

#pragma unroll
    for (int hh = 0; hh < 2; ++hh) {
#pragma unroll
      for (int ch = 0; ch < 4; ++ch) {
        int ct = 4 * hh + ch;
        int col = 16 * ct + col_lo;
        int colh = 16 * ch + col_lo;
#pragma unroll
        for (int reg = 0; reg < 4; ++reg) {
          float p = bl * dv[reg] * __expf(cs[ct][reg] * TEMP);
          if (prevb && col < rtile0 + reg) p = 0.f;   // band: keep s >= l - 128
          pbuf[(rb + reg) * PPAD + colh] = f2bf(p);
        }
      }
#pragma unroll
      for (int ks = 0; ks < 2; ++ks) {
        short8 ap = frag_ldP(pbuf, rowbase, ks, lane);
        short8 bv[4];
#pragma unroll
        for (int nn = 0; nn < 4; ++nn)
          bv[nn] = frag_ldT(kv, 16 * nn, 8 * hh + ks * 4 + (lane >> 4), lane);
#pragma unroll
        for (int nn = 0; nn < 4; ++nn)
          accS[nn] = __builtin_amdgcn_mfma_f32_16x16x32_bf16(ap, bv[nn], accS[nn], 0, 0, 0);
      }
    }
  }

  // ---- final store: out = (1-b)*LV + b*SV ----
#pragma unroll
  for (int nn = 0; nn < 4; ++nn)
#pragma unroll
    for (int reg = 0; reg < 4; ++reg)
      out[qgbase + (rb + reg) * ROWSTRIDE + 16 * nn + col_lo] = accL[nn][reg] + accS[nn][reg];
}

extern "C" void kernel_launch(void* const* d_in, const int* in_sizes, int n_in,
                              void* d_out, int out_size, void* d_ws, size_t ws_size,
                              hipStream_t stream) {
  (void)in_sizes; (void)n_in; (void)out_size; (void)ws_size;
  const float* Q = (const float*)d_in[0];
  const float* K = (const float*)d_in[1];
  const float* V = (const float*)d_in[2];
  const float* mask = (const float*)d_in[3];
  const float* blend = (const float*)d_in[4];
  float* out = (float*)d_out;
  float* ws = (float*)d_ws;
  // layout: [0, NCHUNKS*CHUNK_WS) chunk state (4.26 MB); then partials (2.1 MB).
  float* part = ws + (size_t)NCHUNKS * CHUNK_WS;   // needs ws_size >= 6.4 MB

  k_chunksums<<<dim3(N_ * H_ * NC), dim3(256), 0, stream>>>(K, V, mask, ws);
  k_scan<<<dim3(N_ * H_), dim3(256), 0, stream>>>(ws);
  k_denom<<<dim3(N_ * H_ * 136), dim3(256), 0, stream>>>(Q, K, mask, part);
  k_fused<<<dim3(N_ * H_ * NC * 2), dim3(256), 0, stream>>>(Q, K, V, mask, blend, ws, part, out);
}

// Round 5
// 49.099 us; speedup vs baseline: 10.5404x; 1.7679x over previous
//
#include <hip/hip_runtime.h>
#include <math.h>

#define N_ 2
#define L_ 2048
#define H_ 8
#define E_ 64
#define D_ 64
#define C_ 128                 // chunk size
#define NC (L_/C_)             // 16
#define ROWSTRIDE (H_*E_)      // 512 floats between consecutive l
#define TEMP 0.125f            // 1/sqrt(64)
#define EPS_F 1e-6f
#define NEG_INF_F (-1e9f)
#define CHUNK_WS (E_*D_ + E_)  // 4160 floats per (n,h,chunk) ws entry
#define NCHUNKS (N_*H_*NC)     // 256
#define TPAD 136               // transposed bf16 tile row stride (shorts)
#define PPAD 72                // pbuf row stride (shorts)

typedef __attribute__((ext_vector_type(8))) short short8;   // 8 bf16 in 4 VGPRs
typedef __attribute__((ext_vector_type(4))) float f32x4;

__device__ __forceinline__ short f2bf(float x) {
  unsigned u = __float_as_uint(x);
  u += 0x7fffu + ((u >> 16) & 1u);   // round-to-nearest-even
  return (short)(u >> 16);
}
__device__ __forceinline__ float bf2f(short s) {
  return __uint_as_float(((unsigned)(unsigned short)s) << 16);
}
// tanh(x)+1 = 2/(1+exp(-2x)) — ~5 VALU ops vs ~35 for precise tanhf
__device__ __forceinline__ float tanh1f(float x) {
  float e = __expf(-2.f * x);
  return 2.f * __builtin_amdgcn_rcpf(1.f + e);
}

// Load a [128][64] f32 tile (rows stride 512 in global) into LDS with row stride RS.
template <int RS, typename F>
__device__ __forceinline__ void load_tile(float* __restrict__ dst,
                                          const float* __restrict__ src_base,
                                          F f) {
  const int t = threadIdx.x;
#pragma unroll
  for (int k = 0; k < 8; ++k) {
    int idx4 = k * 256 + t;
    int s = idx4 >> 4;
    int e = (idx4 & 15) << 2;
    float4 v = *(const float4*)(src_base + s * ROWSTRIDE + e);
    v = f(v, s);
    *(float4*)(dst + s * RS + e) = v;
  }
}

// Load [128][64] f32 global tile -> bf16 LDS tile with XOR granule swizzle.
__device__ __forceinline__ void load_bf16_tile(short* __restrict__ dst,
                                               const float* __restrict__ src) {
  const int t = threadIdx.x;
#pragma unroll
  for (int it = 0; it < 4; ++it) {
    int gi = it * 256 + t;
    int row = gi >> 3, g = gi & 7;
    const float* p = src + row * ROWSTRIDE + g * 8;
    float4 a = *(const float4*)p;
    float4 b = *(const float4*)(p + 4);
    short8 v;
    v[0] = f2bf(a.x); v[1] = f2bf(a.y); v[2] = f2bf(a.z); v[3] = f2bf(a.w);
    v[4] = f2bf(b.x); v[5] = f2bf(b.y); v[6] = f2bf(b.z); v[7] = f2bf(b.w);
    int sg = g ^ (row & 7);
    *(short8*)(dst + row * 64 + sg * 8) = v;
  }
}

// A/B fragment from swizzled row-major bf16 tile ([rows][64], granule XOR swizzle).
__device__ __forceinline__ short8 frag_ld(const short* __restrict__ buf,
                                          int rowbase, int hf, int lane) {
  int r = rowbase + (lane & 15);
  int g = (hf * 4 + (lane >> 4)) ^ (r & 7);
  return *(const short8*)(buf + r * 64 + g * 8);
}
// B fragment from transposed padded tile [64][TPAD].
__device__ __forceinline__ short8 frag_ldT(const short* __restrict__ buf,
                                           int nbase, int g, int lane) {
  int r = nbase + (lane & 15);
  return *(const short8*)(buf + r * TPAD + g * 8);
}
// A fragment from pbuf [64][PPAD].
__device__ __forceinline__ short8 frag_ldP(const short* __restrict__ buf,
                                           int rowbase, int ks, int lane) {
  int r = rowbase + (lane & 15);
  int g = ks * 4 + (lane >> 4);
  return *(const short8*)(buf + r * PPAD + g * 8);
}

// ---------------- Kernel 1: per-chunk local sums  sum K1 (E) and sum K1⊗V (E x D) ----
extern "C" __global__ void __launch_bounds__(256)
k_chunksums(const float* __restrict__ K, const float* __restrict__ V,
            const float* __restrict__ mask, float* __restrict__ ws) {
  __shared__ float kbuf[C_ * E_];
  __shared__ float vbuf[C_ * E_];
  const int orig = blockIdx.x;                       // 256 = 8 * 32
  const int swz = (orig & 7) * 32 + (orig >> 3);     // XCD x gets nh {2x,2x+1}
  const int c = swz & (NC - 1), nh = swz >> 4, h = nh & (H_ - 1), n = nh >> 3;
  const int t = threadIdx.x;
  const int gbase = ((n * L_ + c * C_) * H_ + h) * E_;
  const float* mrow = mask + n * L_ + c * C_;

  load_tile<E_>(kbuf, K + gbase, [&](float4 v, int s) {
    float km = mrow[s];
    v.x = tanh1f(v.x) * km; v.y = tanh1f(v.y) * km;
    v.z = tanh1f(v.z) * km; v.w = tanh1f(v.w) * km;
    return v;
  });
  load_tile<E_>(vbuf, V + gbase, [&](float4 v, int) { return v; });
  __syncthreads();

  const int e0 = (t >> 4) << 2, d0 = (t & 15) << 2;
  float acc[4][4] = {};
  for (int s = 0; s < C_; ++s) {
    float4 kk = *(const float4*)(kbuf + s * E_ + e0);
    float4 vv = *(const float4*)(vbuf + s * E_ + d0);
    float ka[4] = {kk.x, kk.y, kk.z, kk.w};
    float va[4] = {vv.x, vv.y, vv.z, vv.w};
#pragma unroll
    for (int a = 0; a < 4; ++a)
#pragma unroll
      for (int b = 0; b < 4; ++b) acc[a][b] += ka[a] * va[b];
  }
  float* wsc = ws + (size_t)(nh * NC + c) * CHUNK_WS;
#pragma unroll
  for (int a = 0; a < 4; ++a) {
    float4 st = {acc[a][0], acc[a][1], acc[a][2], acc[a][3]};
    *(float4*)(wsc + (e0 + a) * D_ + d0) = st;
  }
  if (t < E_) {
    float sum = 0.f;
    for (int s = 0; s < C_; ++s) sum += kbuf[s * E_ + t];
    wsc[E_ * D_ + t] = sum;
  }
}

// ---------------- Kernel 2: exclusive prefix scan, element-parallel ------------------
// grid = 16 nh * 17 segments = 272 blocks; each thread owns ONE element's 16-chunk scan.
extern "C" __global__ void __launch_bounds__(256)
k_scan(float* __restrict__ ws) {
  const int bid = blockIdx.x;                        // 272 = 8 * 34
  const int swz = (bid & 7) * 34 + (bid >> 3);
  const int nh = swz / 17, seg = swz - nh * 17;
  const int idx = seg * 256 + threadIdx.x;
  if (idx >= CHUNK_WS) return;
  float* base = ws + (size_t)nh * NC * CHUNK_WS + idx;
  float v[NC];
#pragma unroll
  for (int c = 0; c < NC; ++c) v[c] = base[(size_t)c * CHUNK_WS];
  float acc = 0.f;
#pragma unroll
  for (int c = 0; c < NC; ++c) {
    base[(size_t)c * CHUNK_WS] = acc;
    acc += v[c];
  }
}

// ---------------- Kernel 3: denominator partials via bf16 MFMA -----------------------
// part[((nh*16+qb)*128 + l)*16 + kb] = sum_s exp(temp*(QK + masks))  (row-contiguous kb)
extern "C" __global__ void __launch_bounds__(256)
k_denom(const float* __restrict__ Q, const float* __restrict__ K,
        const float* __restrict__ mask, float* __restrict__ part) {
  __shared__ short qlds[C_ * E_];
  __shared__ short klds[C_ * E_];
  __shared__ float kmsk[C_];
  const int orig = blockIdx.x;                       // 2176 = 8 * 272
  const int swz = (orig & 7) * 272 + (orig >> 3);    // XCD x gets nh {2x,2x+1}
  const int nh = swz / 136;
  const int p = swz - nh * 136;
  int qb = (int)((sqrtf(8.f * p + 1.f) - 1.f) * 0.5f);
  while ((qb + 1) * (qb + 2) / 2 <= p) ++qb;
  while (qb * (qb + 1) / 2 > p) --qb;
  const int kb = p - qb * (qb + 1) / 2;
  const int h = nh & (H_ - 1), n = nh >> 3;
  const int t = threadIdx.x;

  load_bf16_tile(qlds, Q + ((n * L_ + qb * C_) * H_ + h) * E_);
  load_bf16_tile(klds, K + ((n * L_ + kb * C_) * H_ + h) * E_);
  if (t < C_) kmsk[t] = mask[n * L_ + kb * C_ + t];
  __syncthreads();

  const int w = t >> 6, lane = t & 63;
  const int rowbase = w * 32;

  short8 afr[2][2];
#pragma unroll
  for (int m = 0; m < 2; ++m)
#pragma unroll
    for (int hh = 0; hh < 2; ++hh)
      afr[m][hh] = frag_ld(qlds, rowbase + 16 * m, hh, lane);

  f32x4 acc[2][8];
#pragma unroll
  for (int m = 0; m < 2; ++m)
#pragma unroll
    for (int c = 0; c < 8; ++c) acc[m][c] = (f32x4){0.f, 0.f, 0.f, 0.f};

#pragma unroll
  for (int c = 0; c < 8; ++c) {
    short8 b0 = frag_ld(klds, 16 * c, 0, lane);
    short8 b1 = frag_ld(klds, 16 * c, 1, lane);
#pragma unroll
    for (int m = 0; m < 2; ++m) {
      acc[m][c] = __builtin_amdgcn_mfma_f32_16x16x32_bf16(afr[m][0], b0, acc[m][c], 0, 0, 0);
      acc[m][c] = __builtin_amdgcn_mfma_f32_16x16x32_bf16(afr[m][1], b1, acc[m][c], 0, 0, 0);
    }
  }

  const bool diag = (kb == qb);
  const int col_lo = lane & 15;
  float* pout = part + (size_t)(nh * NC + qb) * C_ * 16;
#pragma unroll
  for (int m = 0; m < 2; ++m) {
    const int rbase = rowbase + 16 * m + (lane >> 4) * 4;
    float rs[4] = {0.f, 0.f, 0.f, 0.f};
#pragma unroll
    for (int c = 0; c < 8; ++c) {
      const int col = 16 * c + col_lo;
      const float madd = (kmsk[col] > 0.f) ? 0.f : NEG_INF_F;
#pragma unroll
      for (int reg = 0; reg < 4; ++reg) {
        float x = acc[m][c][reg] + madd;
        if (diag && col > rbase + reg) x += NEG_INF_F;
        rs[reg] += __expf(x * TEMP);
      }
    }
#pragma unroll
    for (int off = 1; off < 16; off <<= 1) {
#pragma unroll
      for (int reg = 0; reg < 4; ++reg) rs[reg] += __shfl_xor(rs[reg], off);
    }
    if (col_lo == 0) {
#pragma unroll
      for (int reg = 0; reg < 4; ++reg) pout[(rbase + reg) * 16 + kb] = rs[reg];
    }
  }
}

// ---------------- Kernel 4: fused linear + banded-softmax, 4-6 barriers --------------
extern "C" __global__ void __launch_bounds__(256, 2)
k_fused(const float* __restrict__ Q, const float* __restrict__ K,
        const float* __restrict__ V, const float* __restrict__ mask,
        const float* __restrict__ blend, const float* __restrict__ ws,
        const float* __restrict__ part, float* __restrict__ out) {
  __shared__ short qs[64 * 64];      // raw Q bf16 (swizzled rows)
  __shared__ short q1[64 * 64];      // tanh(Q)+1 bf16
  __shared__ short kA[C_ * 64];      // K1 (linear)  -> raw K_prev (band)
  __shared__ short kB[C_ * 64];      // raw K_cur (diag band tile), staged once
  __shared__ short kv[64 * TPAD];    // S^T -> V^T_cur -> V^T_prev
  __shared__ short pbuf[64 * PPAD];  // wave-private P half-tiles
  __shared__ float zlds[64];
  __shared__ float dinv[64];
  __shared__ float ksum[E_];
  __shared__ float kmskC[C_];
  __shared__ float kmskP[C_];

  const int orig = blockIdx.x;                      // 512 = 8 * 64
  const int swz = (orig & 7) * 64 + (orig >> 3);    // XCD x gets nh {2x,2x+1}
  const int rh = swz & 1, qb = (swz >> 1) & (NC - 1), nh = swz >> 5;
  const int h = nh & (H_ - 1), n = nh >> 3;
  const int t = threadIdx.x;
  const int w = t >> 6, lane = t & 63;
  const int rowbase = w * 16;
  const int col_lo = lane & 15;
  const int rb = rowbase + ((lane >> 4) << 2);
  const int rtile0 = rh * 64 + rb;
  const int qgbase = ((n * L_ + qb * C_ + rh * 64) * H_ + h) * E_;
  const int kbase_chunk = ((n * L_ + qb * C_) * H_ + h) * E_;
  const float* wsc = ws + (size_t)(nh * NC + qb) * CHUNK_WS;
  const float bl = blend[0];
  const float ob = 1.f - bl;

  // ============== seg1: issue ALL independent staging ==============
#pragma unroll
  for (int it = 0; it < 2; ++it) {
    int gi = it * 256 + t, row = gi >> 3, g = gi & 7;
    const float* p = Q + qgbase + row * ROWSTRIDE + g * 8;
    float4 a = *(const float4*)p, b = *(const float4*)(p + 4);
    float xs[8] = {a.x, a.y, a.z, a.w, b.x, b.y, b.z, b.w};
    short8 vs, v1;
#pragma unroll
    for (int j = 0; j < 8; ++j) { vs[j] = f2bf(xs[j]); v1[j] = f2bf(tanh1f(xs[j])); }
    int sg = g ^ (row & 7);
    *(short8*)(qs + row * 64 + sg * 8) = vs;
    *(short8*)(q1 + row * 64 + sg * 8) = v1;
  }
  {
    const float* mrow = mask + n * L_ + qb * C_;
#pragma unroll
    for (int it = 0; it < 4; ++it) {
      int gi = it * 256 + t, row = gi >> 3, g = gi & 7;
      const float* p = K + kbase_chunk + row * ROWSTRIDE + g * 8;
      float4 a = *(const float4*)p, b = *(const float4*)(p + 4);
      float km = mrow[row];
      float xs[8] = {a.x, a.y, a.z, a.w, b.x, b.y, b.z, b.w};
      short8 vr, v1;
#pragma unroll
      for (int j = 0; j < 8; ++j) { vr[j] = f2bf(xs[j]); v1[j] = f2bf(tanh1f(xs[j]) * km); }
      int sg = g ^ (row & 7);
      *(short8*)(kB + row * 64 + sg * 8) = vr;
      *(short8*)(kA + row * 64 + sg * 8) = v1;
    }
  }
  {  // S^T into kv (read from ws, L2-resident)
    int d = t & 63, eb = t >> 6;
#pragma unroll
    for (int q = 0; q < 2; ++q) {
      int e0 = eb * 16 + q * 8;
      short8 v;
#pragma unroll
      for (int j = 0; j < 8; ++j) v[j] = f2bf(wsc[(e0 + j) * D_ + d]);
      *(short8*)(kv + d * TPAD + (e0 >> 3) * 8) = v;
    }
  }
  float vcur[32];   // V chunk prefetched to regs; LDS-written at seg4
  {
    int d = t & 63, sb = t >> 6;
#pragma unroll
    for (int q = 0; q < 4; ++q)
#pragma unroll
      for (int j = 0; j < 8; ++j)
        vcur[q * 8 + j] = V[kbase_chunk + (sb * 32 + q * 8 + j) * ROWSTRIDE + d];
  }
  if (t < E_) ksum[t] = wsc[E_ * D_ + t];
  if (t < C_) kmskC[t] = mask[n * L_ + qb * C_ + t];
  if (t < 64) {   // dinv: 4 vector loads + masked unrolled sum (no serial chain)
    const float* pb = part + ((size_t)(nh * NC + qb) * C_ + rh * 64 + t) * 16;
    float4 a = *(const float4*)pb, b = *(const float4*)(pb + 4);
    float4 c = *(const float4*)(pb + 8), d4 = *(const float4*)(pb + 12);
    float vv[16] = {a.x, a.y, a.z, a.w, b.x, b.y, b.z, b.w,
                    c.x, c.y, c.z, c.w, d4.x, d4.y, d4.z, d4.w};
    float s = 0.f;
#pragma unroll
    for (int j = 0; j < 16; ++j) s += (j <= qb) ? vv[j] : 0.f;
    dinv[t] = 1.f / s;
  }
  __syncthreads();   // B1

  // ============== seg2: linear QK + zpart + rowsum (no barrier to seg3) ==============
  short8 af1[2], afs[2];
#pragma unroll
  for (int kh = 0; kh < 2; ++kh) {
    af1[kh] = frag_ld(q1, rowbase, kh, lane);
    afs[kh] = frag_ld(qs, rowbase, kh, lane);
  }
  f32x4 c1[8];
#pragma unroll
  for (int ct = 0; ct < 8; ++ct) c1[ct] = (f32x4){0.f, 0.f, 0.f, 0.f};
#pragma unroll
  for (int ct = 0; ct < 8; ++ct) {
    short8 b0 = frag_ld(kA, 16 * ct, 0, lane);
    short8 b1 = frag_ld(kA, 16 * ct, 1, lane);
    c1[ct] = __builtin_amdgcn_mfma_f32_16x16x32_bf16(af1[0], b0, c1[ct], 0, 0, 0);
    c1[ct] = __builtin_amdgcn_mfma_f32_16x16x32_bf16(af1[1], b1, c1[ct], 0, 0, 0);
  }
  if (t < 64) {   // zpart = Q1 . Ksum_start
    float zz = 0.f;
#pragma unroll
    for (int gg = 0; gg < 8; ++gg) {
      int g = (gg + (t >> 3)) & 7;
      short8 v = *(const short8*)(q1 + t * 64 + ((g ^ (t & 7)) * 8));
#pragma unroll
      for (int j = 0; j < 8; ++j) zz += bf2f(v[j]) * ksum[g * 8 + j];
    }
    zlds[t] = zz;
  }
  float rs[4] = {0.f, 0.f, 0.f, 0.f};
#pragma unroll
  for (int ct = 0; ct < 8; ++ct) {
    int col = 16 * ct + col_lo;
#pragma unroll
    for (int reg = 0; reg < 4; ++reg) {
      if (col <= rtile0 + reg) rs[reg] += c1[ct][reg];
      else c1[ct][reg] = 0.f;
    }
  }
#pragma unroll
  for (int off = 1; off < 16; off <<= 1)
#pragma unroll
    for (int reg = 0; reg < 4; ++reg) rs[reg] += __shfl_xor(rs[reg], off);

  // ============== seg3: accL = Q1 @ S_start (kv = S^T) ==============
  f32x4 accL[4];
#pragma unroll
  for (int nn = 0; nn < 4; ++nn) accL[nn] = (f32x4){0.f, 0.f, 0.f, 0.f};
#pragma unroll
  for (int ks = 0; ks < 2; ++ks) {
    short8 bf[4];
#pragma unroll
    for (int nn = 0; nn < 4; ++nn)
      bf[nn] = frag_ldT(kv, 16 * nn, ks * 4 + (lane >> 4), lane);
#pragma unroll
    for (int nn = 0; nn < 4; ++nn)
      accL[nn] = __builtin_amdgcn_mfma_f32_16x16x32_bf16(af1[ks], bf[nn], accL[nn], 0, 0, 0);
  }
  __syncthreads();   // B3: kv S^T -> V^T_cur

  // ============== seg4: write prefetched V chunk to kv ==============
  {
    int d = t & 63, sb = t >> 6;
#pragma unroll
    for (int q = 0; q < 4; ++q) {
      short8 v;
#pragma unroll
      for (int j = 0; j < 8; ++j) v[j] = f2bf(vcur[q * 8 + j]);
      *(short8*)(kv + d * TPAD + ((sb * 32 + q * 8) >> 3) * 8) = v;
    }
  }
  __syncthreads();   // B4

  // ============== seg5: linear PV + diag QK/exp/PV (no barriers inside) ==============
  const bool haveprev = (qb > 0);
  const int kgp = ((n * L_ + (qb - 1) * C_) * H_ + h) * E_;
  float vpre[32];
  if (haveprev) {   // prefetch prev V while MFMAs run
    int d = t & 63, sb = t >> 6;
#pragma unroll
    for (int q = 0; q < 4; ++q)
#pragma unroll
      for (int j = 0; j < 8; ++j)
        vpre[q * 8 + j] = V[kgp + (sb * 32 + q * 8 + j) * ROWSTRIDE + d];
  }
  // linear PV: accL += tril(Q1K1^T)_bf16 @ V
#pragma unroll
  for (int hh = 0; hh < 2; ++hh) {
#pragma unroll
    for (int ch = 0; ch < 4; ++ch) {
      int ct = 4 * hh + ch, colh = 16 * ch + col_lo;
#pragma unroll
      for (int reg = 0; reg < 4; ++reg)
        pbuf[(rb + reg) * PPAD + colh] = f2bf(c1[ct][reg]);
    }
#pragma unroll
    for (int ks = 0; ks < 2; ++ks) {
      short8 ap = frag_ldP(pbuf, rowbase, ks, lane);
      short8 bv[4];
#pragma unroll
      for (int nn = 0; nn < 4; ++nn)
        bv[nn] = frag_ldT(kv, 16 * nn, 8 * hh + ks * 4 + (lane >> 4), lane);
#pragma unroll
      for (int nn = 0; nn < 4; ++nn)
        accL[nn] = __builtin_amdgcn_mfma_f32_16x16x32_bf16(ap, bv[nn], accL[nn], 0, 0, 0);
    }
  }
  // diag tile: QK (kB, staged at seg1) -> exp -> PV (kv = V^T_cur still valid)
  f32x4 accS[4];
#pragma unroll
  for (int nn = 0; nn < 4; ++nn) accS[nn] = (f32x4){0.f, 0.f, 0.f, 0.f};
  {
    f32x4 cs[8];
#pragma unroll
    for (int ct = 0; ct < 8; ++ct) cs[ct] = (f32x4){0.f, 0.f, 0.f, 0.f};
#pragma unroll
    for (int ct = 0; ct < 8; ++ct) {
      short8 b0 = frag_ld(kB, 16 * ct, 0, lane);
      short8 b1 = frag_ld(kB, 16 * ct, 1, lane);
      cs[ct] = __builtin_amdgcn_mfma_f32_16x16x32_bf16(afs[0], b0, cs[ct], 0, 0, 0);
      cs[ct] = __builtin_amdgcn_mfma_f32_16x16x32_bf16(afs[1], b1, cs[ct], 0, 0, 0);
    }
#pragma unroll
    for (int ct = 0; ct < 8; ++ct) {
      int col = 16 * ct + col_lo;
      float madd = (kmskC[col] > 0.f) ? 0.f : NEG_INF_F;
#pragma unroll
      for (int reg = 0; reg < 4; ++reg) {
        float x = cs[ct][reg] + madd;
        if (col > rtile0 + reg) x += NEG_INF_F;   // causal (diag tile)
        cs[ct][reg] = __expf(x * TEMP);           // unnormalized P
      }
    }
#pragma unroll
    for (int hh = 0; hh < 2; ++hh) {
#pragma unroll
      for (int ch = 0; ch < 4; ++ch) {
        int ct = 4 * hh + ch, colh = 16 * ch + col_lo;
#pragma unroll
        for (int reg = 0; reg < 4; ++reg)
          pbuf[(rb + reg) * PPAD + colh] = f2bf(cs[ct][reg]);
      }
#pragma unroll
      for (int ks = 0; ks < 2; ++ks) {
        short8 ap = frag_ldP(pbuf, rowbase, ks, lane);
        short8 bv[4];
#pragma unroll
        for (int nn = 0; nn < 4; ++nn)
          bv[nn] = frag_ldT(kv, 16 * nn, 8 * hh + ks * 4 + (lane >> 4), lane);
#pragma unroll
        for (int nn = 0; nn < 4; ++nn)
          accS[nn] = __builtin_amdgcn_mfma_f32_16x16x32_bf16(ap, bv[nn], accS[nn], 0, 0, 0);
      }
    }
  }

  // ============== seg6/7: prev band tile (qb > 0) ==============
  if (haveprev) {
    __syncthreads();   // B5: kA/kv/kmskP reuse
#pragma unroll
    for (int it = 0; it < 4; ++it) {
      int gi = it * 256 + t, row = gi >> 3, g = gi & 7;
      const float* p = K + kgp + row * ROWSTRIDE + g * 8;
      float4 a = *(const float4*)p, b = *(const float4*)(p + 4);
      short8 vr;
      vr[0] = f2bf(a.x); vr[1] = f2bf(a.y); vr[2] = f2bf(a.z); vr[3] = f2bf(a.w);
      vr[4] = f2bf(b.x); vr[5] = f2bf(b.y); vr[6] = f2bf(b.z); vr[7] = f2bf(b.w);
      int sg = g ^ (row & 7);
      *(short8*)(kA + row * 64 + sg * 8) = vr;
    }
    {
      int d = t & 63, sb = t >> 6;
#pragma unroll
      for (int q = 0; q < 4; ++q) {
        short8 v;
#pragma unroll
        for (int j = 0; j < 8; ++j) v[j] = f2bf(vpre[q * 8 + j]);
        *(short8*)(kv + d * TPAD + ((sb * 32 + q * 8) >> 3) * 8) = v;
      }
    }
    if (t < C_) kmskP[t] = mask[n * L_ + (qb - 1) * C_ + t];
    __syncthreads();   // B6

    f32x4 cs[8];
#pragma unroll
    for (int ct = 0; ct < 8; ++ct) cs[ct] = (f32x4){0.f, 0.f, 0.f, 0.f};
#pragma unroll
    for (int ct = 0; ct < 8; ++ct) {
      short8 b0 = frag_ld(kA, 16 * ct, 0, lane);
      short8 b1 = frag_ld(kA, 16 * ct, 1, lane);
      cs[ct] = __builtin_amdgcn_mfma_f32_16x16x32_bf16(afs[0], b0, cs[ct], 0, 0, 0);
      cs[ct] = __builtin_amdgcn_mfma_f32_16x16x32_bf16(afs[1], b1, cs[ct], 0, 0, 0);
    }
#pragma unroll
    for (int ct = 0; ct < 8; ++ct) {
      int col = 16 * ct + col_lo;
      float madd = (kmskP[col] > 0.f) ? 0.f : NEG_INF_F;
#pragma unroll
      for (int reg = 0; reg < 4; ++reg) {
        float x = cs[ct][reg] + madd;     // no causal mask on prev tile
        float pp = __expf(x * TEMP);
        if (col < rtile0 + reg) pp = 0.f; // band: keep s >= l - 128
        cs[ct][reg] = pp;
      }
    }
#pragma unroll
    for (int hh = 0; hh < 2; ++hh) {
#pragma unroll
      for (int ch = 0; ch < 4; ++ch) {
        int ct = 4 * hh + ch, colh = 16 * ch + col_lo;
#pragma unroll
        for (int reg = 0; reg < 4; ++reg)
          pbuf[(rb + reg) * PPAD + colh] = f2bf(cs[ct][reg]);
      }
#pragma unroll
      for (int ks = 0; ks < 2; ++ks) {
        short8 ap = frag_ldP(pbuf, rowbase, ks, lane);
        short8 bv[4];
#pragma unroll
        for (int nn = 0; nn < 4; ++nn)
          bv[nn] = frag_ldT(kv, 16 * nn, 8 * hh + ks * 4 + (lane >> 4), lane);
#pragma unroll
        for (int nn = 0; nn < 4; ++nn)
          accS[nn] = __builtin_amdgcn_mfma_f32_16x16x32_bf16(ap, bv[nn], accS[nn], 0, 0, 0);
      }
    }
  }

  // ============== final: out = ob*z*(LV_raw) + bl*dinv*SV_raw ==============
  float zrf[4], sdv[4];
#pragma unroll
  for (int reg = 0; reg < 4; ++reg) {
    zrf[reg] = ob / (zlds[rb + reg] + rs[reg] + EPS_F);
    sdv[reg] = bl * dinv[rb + reg];
  }
#pragma unroll
  for (int nn = 0; nn < 4; ++nn)
#pragma unroll
    for (int reg = 0; reg < 4; ++reg)
      out[qgbase + (rb + reg) * ROWSTRIDE + 16 * nn + col_lo] =
          zrf[reg] * accL[nn][reg] + sdv[reg] * accS[nn][reg];
}

extern "C" void kernel_launch(void* const* d_in, const int* in_sizes, int n_in,
                              void* d_out, int out_size, void* d_ws, size_t ws_size,
                              hipStream_t stream) {
  (void)in_sizes; (void)n_in; (void)out_size; (void)ws_size;
  const float* Q = (const float*)d_in[0];
  const float* K = (const float*)d_in[1];
  const float* V = (const float*)d_in[2];
  const float* mask = (const float*)d_in[3];
  const float* blend = (const float*)d_in[4];
  float* out = (float*)d_out;
  float* ws = (float*)d_ws;
  float* part = ws + (size_t)NCHUNKS * CHUNK_WS;   // 4.26 MB + 2 MB = 6.26 MB total

  k_denom<<<dim3(N_ * H_ * 136), dim3(256), 0, stream>>>(Q, K, mask, part);
  k_chunksums<<<dim3(N_ * H_ * NC), dim3(256), 0, stream>>>(K, V, mask, ws);
  k_scan<<<dim3(272), dim3(256), 0, stream>>>(ws);
  k_fused<<<dim3(N_ * H_ * NC * 2), dim3(256), 0, stream>>>(Q, K, V, mask, blend, ws, part, out);
}